// Round 12
// baseline (309.004 us; speedup 1.0000x reference)
//
#include <hip/hip_runtime.h>
#include <cstdint>
#include <cstddef>

#define NPTS 16384
#define KSEL 4096
#define HIDDEN 128
#define NHEADS 8
#define DHEAD 16
#define OUTD 256
#define NSLICE 4   // k/q slices for attn partials
#define FCAP 131072
#define LCAP 512
#define TAU 0.2f
#define SBITS 13
#define SBINS 8192

typedef __attribute__((ext_vector_type(8))) short bf16x8;
typedef __attribute__((ext_vector_type(4))) float f32x4;
typedef __attribute__((ext_vector_type(16))) float f32x16;

#if defined(__has_builtin)
#if __has_builtin(__builtin_amdgcn_exp2f)
#define E2(x) __builtin_amdgcn_exp2f(x)
#endif
#endif
#ifndef E2
#define E2(x) exp2f(x)
#endif

// ---- workspace layout (bytes) ----
constexpr size_t OFF_PA    = 1024;                         // NPTS*16 bf16 (A-side packed)
constexpr size_t OFF_PB    = OFF_PA  + (size_t)NPTS*32;    // NPTS*16 bf16 (B-side packed)
constexpr size_t OFF_SQ    = OFF_PB  + (size_t)NPTS*32;
constexpr size_t OFF_DL    = OFF_SQ  + (size_t)NPTS*4;
constexpr size_t OFF_CNT   = OFF_DL  + (size_t)NPTS*4;     // int (zeroed by k_prep)
constexpr size_t OFF_NFLAG = OFF_CNT + (size_t)NPTS*4;     // uint[0]=nflag,[1]=colsum done,[2]=select done
constexpr size_t OFF_FLG   = OFF_NFLAG + 1024;             // FCAP uints
constexpr size_t OFF_SEL   = OFF_FLG + (size_t)FCAP*4;     // KSEL int
constexpr size_t SZ_PK     = (size_t)NHEADS*KSEL*32*2;     // 2 MB packed [hi16|lo16] bf16
constexpr size_t OFF_QPK   = OFF_SEL + (size_t)KSEL*4;
constexpr size_t OFF_KPK   = OFF_QPK + SZ_PK;
constexpr size_t OFF_V     = OFF_KPK + SZ_PK;                      // KSEL*128 f32
constexpr size_t OFF_LP    = OFF_V  + (size_t)KSEL*HIDDEN*4;       // 8*4096*4 f32 partial l
constexpr size_t OFF_RL    = OFF_LP + (size_t)NHEADS*KSEL*NSLICE*4; // reused: ghist(32KB)+gkeys(64KB)
constexpr size_t OFF_WP    = OFF_RL + (size_t)NHEADS*KSEL*4;        // 8*4096*4 f32 partial w
constexpr size_t OFF_PAV   = OFF_WP + (size_t)NHEADS*KSEL*NSLICE*4; // 128 f32
constexpr size_t OFF_GH    = OFF_RL;                       // SBINS uints (32 KB)
constexpr size_t OFF_GK    = OFF_RL + 32768;               // NPTS uints (64 KB)

__device__ __forceinline__ unsigned short f2bf(float f) {
    union { float f; unsigned u; } v; v.f = f;
    unsigned r = v.u + 0x7fffu + ((v.u >> 16) & 1u);
    return (unsigned short)(r >> 16);
}
__device__ __forceinline__ float bf2f(unsigned short h) {
    union { unsigned u; float f; } v; v.u = ((unsigned)h) << 16;
    return v.f;
}

// ---- 1. prep: ligand center, sq, d_lig, packed hi/lo coords; zeroes cnt/flags/ghist/pav ----
// A-side s-slot carries (s - 9.0) so the neighbor MFMA emits c = d^2 - 9 directly.
__global__ void __launch_bounds__(256) k_prep(const float* __restrict__ pos, const float* __restrict__ lig, int M,
                       unsigned short* __restrict__ pa, unsigned short* __restrict__ pb,
                       float* __restrict__ sq, float* __restrict__ dl, float* __restrict__ pav,
                       int* __restrict__ cnt, unsigned int* __restrict__ nfl,
                       unsigned int* __restrict__ ghist) {
    __shared__ float ls[128];
    __shared__ float ctr[3];
    int tid = threadIdx.x;
    if (blockIdx.x == 0) {
        if (tid < HIDDEN) pav[tid] = 0.f;
        if (tid < 3) nfl[tid] = 0;           // nflag + colsum-done + select-done
    }
    {
        int gz = blockIdx.x * 256 + tid;
        if (gz < SBINS) ghist[gz] = 0;
    }
    for (int i = tid; i < 3 * M; i += 256) ls[i] = lig[i];
    __syncthreads();
    if (tid < 3) {
        float s = 0.f;
        for (int i = 0; i < M; i++) s += ls[i * 3 + tid];
        ctr[tid] = s / (float)M;
    }
    __syncthreads();
    int i = blockIdx.x * 256 + tid;
    cnt[i] = 0;                              // fused memset
    float x = pos[i*3+0], y = pos[i*3+1], z = pos[i*3+2];
    float s = (x*x + y*y) + z*z;
    sq[i] = s;
    float dx = x - ctr[0], dy = y - ctr[1], dz = z - ctr[2];
    dl[i] = sqrtf((dx*dx + dy*dy) + dz*dz);
    unsigned short xh = f2bf(x); float xr = bf2f(xh); float xl = x - xr;
    unsigned short yh = f2bf(y); float yr = bf2f(yh); float yl = y - yr;
    unsigned short zh = f2bf(z); float zr = bf2f(zh); float zl = z - zr;
    unsigned short xlb = f2bf(xl), ylb = f2bf(yl), zlb = f2bf(zl);
    unsigned short xhA = f2bf(-2.f*xr), xlA = f2bf(-2.f*xl);
    unsigned short yhA = f2bf(-2.f*yr), ylA = f2bf(-2.f*yl);
    unsigned short zhA = f2bf(-2.f*zr), zlA = f2bf(-2.f*zl);
    float sm9 = s - 9.0f;                      // folded threshold (A side only)
    unsigned short sihA = f2bf(sm9);
    unsigned short silA = f2bf(sm9 - bf2f(sihA));
    unsigned short sih = f2bf(s);
    unsigned short sil = f2bf(s - bf2f(sih));
    unsigned short one = f2bf(1.0f);
    union { unsigned short s[16]; float4 f[2]; } A, B;
    // k-slots: per coord (hh, h*lo_j, lo_i*h), 9-11 lo*lo, 12-13 (s_a-9)*1, 14-15 1*s_b
    A.s[0]=xhA; A.s[1]=xhA; A.s[2]=xlA;
    A.s[3]=yhA; A.s[4]=yhA; A.s[5]=ylA;
    A.s[6]=zhA; A.s[7]=zhA; A.s[8]=zlA;
    A.s[9]=xlA; A.s[10]=ylA; A.s[11]=zlA;
    A.s[12]=sihA; A.s[13]=silA; A.s[14]=one; A.s[15]=one;
    B.s[0]=xh;  B.s[1]=xlb;  B.s[2]=xh;
    B.s[3]=yh;  B.s[4]=ylb;  B.s[5]=yh;
    B.s[6]=zh;  B.s[7]=zlb;  B.s[8]=zh;
    B.s[9]=xlb; B.s[10]=ylb; B.s[11]=zlb;
    B.s[12]=one; B.s[13]=one; B.s[14]=sih; B.s[15]=sil;
    float4* pad = (float4*)(pa + (size_t)i * 16);
    pad[0] = A.f[0]; pad[1] = A.f[1];
    float4* pbd = (float4*)(pb + (size_t)i * 16);
    pbd[0] = B.f[0]; pbd[1] = B.f[1];
}

// ---- 2. neighbor counts via ONE 32x32x16 MFMA per 1024 pairs (r5 proven form) ----
__global__ void __launch_bounds__(256) k_neighbor(
        const unsigned short* __restrict__ pa, const unsigned short* __restrict__ pb,
        int* __restrict__ cnt, unsigned int* __restrict__ flg, unsigned int* __restrict__ nflag) {
    __shared__ unsigned short js[256 * 24];     // 48B row stride (16B-aligned halves)
    __shared__ unsigned int fbuf[LCAP];
    __shared__ unsigned int fcnt, fbase;
    int tid = threadIdx.x;
    if (tid == 0) fcnt = 0;
    int lane = tid & 63, w = tid >> 6;
    int half = lane >> 5, il = lane & 31;
    int i = blockIdx.x * 128 + w * 32 + il;
    bf16x8 bfrag = *(const bf16x8*)(pb + (size_t)i * 16 + half * 8);
    int jb0 = blockIdx.y * 1024;
    int acc = 0;
    const f32x16 czero = {0.f,0.f,0.f,0.f,0.f,0.f,0.f,0.f,0.f,0.f,0.f,0.f,0.f,0.f,0.f,0.f};
    for (int chv = 0; chv < 4; chv++) {
        int jb = jb0 + chv * 256;
        __syncthreads();
        {
            const float4* src = (const float4*)(pa + (size_t)(jb + tid) * 16);
            float4 v0 = src[0], v1 = src[1];
            float4* dst = (float4*)&js[tid * 24];
            dst[0] = v0; dst[1] = v1;
        }
        __syncthreads();
        #pragma unroll 2
        for (int t = 0; t < 8; t++) {
            bf16x8 afrag = *(const bf16x8*)&js[(t * 32 + il) * 24 + half * 8];
            f32x16 c = __builtin_amdgcn_mfma_f32_32x32x16_bf16(afrag, bfrag, czero, 0, 0, 0);
            int cs = 0;
            #pragma unroll
            for (int r = 0; r < 16; r++) cs += (c[r] < -TAU);
            acc += cs;
            // min |c| over the 16 columns: fires iff a window element exists
            float a0 = fminf(fabsf(c[0]),  fabsf(c[1]));
            float a1 = fminf(fabsf(c[2]),  fabsf(c[3]));
            float a2 = fminf(fabsf(c[4]),  fabsf(c[5]));
            float a3 = fminf(fabsf(c[6]),  fabsf(c[7]));
            float a4 = fminf(fabsf(c[8]),  fabsf(c[9]));
            float a5 = fminf(fabsf(c[10]), fabsf(c[11]));
            float a6 = fminf(fabsf(c[12]), fabsf(c[13]));
            float a7 = fminf(fabsf(c[14]), fabsf(c[15]));
            float b0 = fminf(a0, a1), b1 = fminf(a2, a3);
            float b2 = fminf(a4, a5), b3 = fminf(a6, a7);
            float mn = fminf(fminf(b0, b1), fminf(b2, b3));
            if (mn <= TAU) {                 // rare: boundary pair(s) in this lane's column
                int jt = jb + t * 32;
                #pragma unroll
                for (int r = 0; r < 16; r++) {
                    float d = c[r];
                    if (d >= -TAU && d < TAU) {
                        int j = jt + (r & 3) + 8 * (r >> 2) + 4 * half;
                        unsigned xx = atomicAdd(&fcnt, 1u);
                        if (xx < LCAP) fbuf[xx] = ((unsigned)i << 14) | (unsigned)j;
                    }
                }
            }
        }
    }
    acc += __shfl_xor(acc, 32);
    if (half == 0) atomicAdd(&cnt[i], acc);
    __syncthreads();
    if (tid == 0) {
        unsigned cf = fcnt; if (cf > LCAP) cf = LCAP;
        fcnt = cf;
        fbase = atomicAdd(nflag, cf);
    }
    __syncthreads();
    unsigned cf = fcnt, fb = fbase;
    for (unsigned xx = tid; xx < cf; xx += 256) {
        unsigned di = fb + xx;
        if (di < FCAP) flg[di] = fbuf[xx];
    }
}

// ---- 2b. resolve boundary-window pairs exactly (fp32) ----
__global__ void __launch_bounds__(256) k_fixup(const float* __restrict__ pos, const float* __restrict__ sq,
        const unsigned int* __restrict__ flg, const unsigned int* __restrict__ nflag,
        int* __restrict__ cnt) {
    int nf = (int)*nflag; if (nf > FCAP) nf = FCAP;
    for (int idx = blockIdx.x * 256 + threadIdx.x; idx < nf; idx += gridDim.x * 256) {
        unsigned pr = flg[idx];
        int i = (int)((pr >> 14) & 16383u), j = (int)(pr & 16383u);
        float xi = pos[i*3+0], yi = pos[i*3+1], zi = pos[i*3+2];
        float xj = pos[j*3+0], yj = pos[j*3+1], zj = pos[j*3+2];
        float dot = fmaf(xi, xj, fmaf(yi, yj, zi * zj));
        float d2 = (sq[i] + sq[j]) - 2.0f * dot;
        if (d2 < 9.0f) atomicAdd(&cnt[i], 1);
    }
}

// ---- 3. multi-block top-KSEL select (last-block pattern) ----
// 16 blocks: private LDS 8192-bin (top-13-bit) hist -> global atomics -> done ctr.
// Last block: suffix-scan ghist (atomic reads, device-coherent) to find threshold
// bin T13 + rem; recompute all scores (reads only prior-kernel data, no cross-
// block plain-store hazard); compact bin>T13 via ballot; exact-rank bin==T13
// candidates by (key desc, idx asc) -- identical semantics to the radix version.
__global__ void __launch_bounds__(1024) k_select(const float* __restrict__ dl, const int* __restrict__ cnt,
        unsigned int* __restrict__ ghist, unsigned int* __restrict__ sdone,
        unsigned int* __restrict__ gkeys, int* __restrict__ sel) {
    __shared__ int lh[SBINS];
    __shared__ int wsum[16];
    __shared__ int s_bin, s_rem, s_nout, s_ncand, isLast;
    __shared__ unsigned int ck[4096];
    __shared__ unsigned short cidx[4096];
    int tid = threadIdx.x, lane = tid & 63, wid = tid >> 6;
    for (int b = tid; b < SBINS; b += 1024) lh[b] = 0;
    __syncthreads();
    {
        int i = blockIdx.x * 1024 + tid;
        float score = 1.0f / (1.0f + dl[i] / 5.0f) + 0.5f * (1.0f / (float)cnt[i]);
        unsigned int u = __float_as_uint(score);
        unsigned int key = u ^ ((u & 0x80000000u) ? 0xFFFFFFFFu : 0x80000000u);
        atomicAdd(&lh[key >> (32 - SBITS)], 1);
    }
    __syncthreads();
    for (int b = tid; b < SBINS; b += 1024) {
        int v = lh[b];
        if (v) atomicAdd(&ghist[b], (unsigned)v);
    }
    __threadfence();
    __syncthreads();
    if (tid == 0) isLast = (atomicAdd(sdone, 1u) == 15u);
    __syncthreads();
    if (!isLast) return;
    // ---- last block only: threshold search ----
    int h8[8]; int tot = 0;
    #pragma unroll
    for (int q = 0; q < 8; q++) { h8[q] = (int)atomicAdd(&ghist[tid * 8 + q], 0u); tot += h8[q]; }
    int s = tot;
    #pragma unroll
    for (int off = 1; off < 64; off <<= 1) {           // wave suffix scan
        int v = __shfl_down(s, off);
        if (lane + off < 64) s += v;
    }
    if (lane == 0) wsum[wid] = s;
    __syncthreads();
    if (tid == 0) {
        int acc2 = 0;
        for (int w2 = 15; w2 >= 0; w2--) { int t2 = wsum[w2]; wsum[w2] = acc2; acc2 += t2; }
        s_nout = 0; s_ncand = 0;
    }
    __syncthreads();
    {
        int after = wsum[wid] + (s - tot);   // count in bins strictly above this thread's bins
        int prev = after;
        #pragma unroll
        for (int q = 7; q >= 0; q--) {
            int cur = prev + h8[q];
            if (cur >= KSEL && prev < KSEL) { s_bin = tid * 8 + q; s_rem = KSEL - prev; }
            prev = cur;
        }
    }
    __syncthreads();
    int T13 = s_bin, rem = s_rem;
    // ---- compact + gather threshold-bin candidates ----
    for (int i = tid; i < NPTS; i += 1024) {
        float score = 1.0f / (1.0f + dl[i] / 5.0f) + 0.5f * (1.0f / (float)cnt[i]);
        unsigned int u = __float_as_uint(score);
        unsigned int key = u ^ ((u & 0x80000000u) ? 0xFFFFFFFFu : 0x80000000u);
        gkeys[i] = key;                      // same-block fallback storage
        int bin = (int)(key >> (32 - SBITS));
        bool take = bin > T13;
        unsigned long long bal = __ballot(take);
        if (bal) {
            int leader = __ffsll((long long)bal) - 1;
            int b0 = 0;
            if (lane == leader) b0 = atomicAdd(&s_nout, __popcll(bal));
            b0 = __shfl(b0, leader);
            if (take) sel[b0 + __popcll(bal & ((1ULL << lane) - 1ULL))] = i;
        }
        bool cand = (bin == T13);
        unsigned long long cb = __ballot(cand);
        if (cb) {
            int leader = __ffsll((long long)cb) - 1;
            int c0 = 0;
            if (lane == leader) c0 = atomicAdd(&s_ncand, __popcll(cb));
            c0 = __shfl(c0, leader);
            if (cand) {
                int pos = c0 + __popcll(cb & ((1ULL << lane) - 1ULL));
                if (pos < 4096) { ck[pos] = key; cidx[pos] = (unsigned short)i; }
            }
        }
    }
    __syncthreads();
    int C = s_ncand;
    if (C <= 4096) {
        // exact rank among candidates: key desc, tie -> lowest index (matches radix+rank)
        for (int c = tid; c < C; c += 1024) {
            unsigned int ki = ck[c]; int ii = (int)cidx[c];
            int rank = 0;
            for (int j = 0; j < C; j++) {
                unsigned int kj = ck[j];
                rank += (int)((kj > ki) || (kj == ki && (int)cidx[j] < ii));
            }
            if (rank < rem) sel[atomicAdd(&s_nout, 1)] = ii;
        }
    } else {
        // pathological fallback (expected never): exact rank via global keys
        for (int i = tid; i < NPTS; i += 1024) {
            unsigned int ki = gkeys[i];
            if ((int)(ki >> (32 - SBITS)) != T13) continue;
            int rank = 0;
            for (int j = 0; j < NPTS; j++) {
                unsigned int kj = gkeys[j];
                if ((int)(kj >> (32 - SBITS)) != T13) continue;
                rank += (int)((kj > ki) || (kj == ki && j < i));
            }
            if (rank < rem) sel[atomicAdd(&s_nout, 1)] = i;
        }
    }
}

// ---- 4. gather + node embed + QKV projections (4 rows/block for 2 waves/SIMD) ----
__device__ __forceinline__ void proj4(const float hs[4][HIDDEN], const float* __restrict__ W,
                                      float b, int d, float* acc) {
    #pragma unroll
    for (int r = 0; r < 4; r++) acc[r] = b;
    for (int c = 0; c < HIDDEN; c += 4) {
        float w0 = W[(c+0)*HIDDEN+d], w1 = W[(c+1)*HIDDEN+d], w2 = W[(c+2)*HIDDEN+d], w3 = W[(c+3)*HIDDEN+d];
        #pragma unroll
        for (int r = 0; r < 4; r++) {
            float4 h4 = *(const float4*)&hs[r][c];
            float a = acc[r];
            a = fmaf(h4.x, w0, a); a = fmaf(h4.y, w1, a); a = fmaf(h4.z, w2, a); a = fmaf(h4.w, w3, a);
            acc[r] = a;
        }
    }
}

__global__ void __launch_bounds__(128) k_qkv(const float* __restrict__ x, const int* __restrict__ sel,
        const float* __restrict__ Wn, const float* __restrict__ bn,
        const float* __restrict__ Wq, const float* __restrict__ bq,
        const float* __restrict__ Wk, const float* __restrict__ bk,
        const float* __restrict__ Wv, const float* __restrict__ bv,
        unsigned short* __restrict__ qpk, unsigned short* __restrict__ kpk,
        float* __restrict__ vg) {
    __shared__ float xs[4][8];
    __shared__ __align__(16) float hs[4][HIDDEN];
    int d = threadIdx.x;
    int r0 = blockIdx.x * 4;
    if (d < 32) { int rr = d >> 3, cc = d & 7; xs[rr][cc] = x[(size_t)sel[r0 + rr] * 8 + cc]; }
    __syncthreads();
    {
        float wn[8];
        #pragma unroll
        for (int c = 0; c < 8; c++) wn[c] = Wn[c * HIDDEN + d];
        float b = bn[d];
        #pragma unroll
        for (int r = 0; r < 4; r++) {
            float a = b;
            #pragma unroll
            for (int c = 0; c < 8; c++) a = fmaf(xs[r][c], wn[c], a);
            hs[r][d] = a;
        }
    }
    __syncthreads();
    int hh = d >> 4, dd = d & 15;
    float acc[4];
    // Q (pre-scaled by log2(e)/4, split hi/lo)
    proj4(hs, Wq, bq[d], d, acc);
    #pragma unroll
    for (int r = 0; r < 4; r++) {
        float val = acc[r] * 0.36067376022224085f;
        unsigned short hi = f2bf(val);
        unsigned short lo = f2bf(val - bf2f(hi));
        size_t idx = ((size_t)(hh * KSEL) + r0 + r) * 32 + dd;
        qpk[idx] = hi; qpk[idx + 16] = lo;
    }
    // K
    proj4(hs, Wk, bk[d], d, acc);
    #pragma unroll
    for (int r = 0; r < 4; r++) {
        float val = acc[r];
        unsigned short hi = f2bf(val);
        unsigned short lo = f2bf(val - bf2f(hi));
        size_t idx = ((size_t)(hh * KSEL) + r0 + r) * 32 + dd;
        kpk[idx] = hi; kpk[idx + 16] = lo;
    }
    // V (fp32, row-major [q][128])
    proj4(hs, Wv, bv[d], d, acc);
    #pragma unroll
    for (int r = 0; r < 4; r++) vg[(size_t)(r0+r)*HIDDEN + d] = acc[r];
}

// ---- 5. phase 1: row sums l_q via MFMA; 512 thr = 8 waves = 128 q-rows/block ----
__global__ void __launch_bounds__(512) k_attn_l(
        const unsigned short* __restrict__ qpk, const unsigned short* __restrict__ kpk,
        float* __restrict__ lp) {
    __shared__ unsigned short smem[256 * 40];
    int tid = threadIdx.x;
    int ks = blockIdx.x, yg = blockIdx.y, h = blockIdx.z;
    size_t hb = (size_t)h * KSEL;
    int lane = tid & 63, w = tid >> 6;      // w in 0..7
    int n = lane & 15, g = lane >> 4;
    int q0w = yg * 128 + w * 16;
    bf16x8 afrag = *(const bf16x8*)(qpk + (hb + q0w + n) * 32 + g * 8); // A=[Qh|Ql]
    float l0 = 0.f, l1 = 0.f, l2 = 0.f, l3 = 0.f;
    int b1off = (g & 1) * 8;
    int b2off = 16 + g * 8;
    for (int kc = 0; kc < 4; kc++) {
        __syncthreads();
        {
            int row = tid >> 1, hf = tid & 1;     // 2 threads per row, 32B each
            int krow = ks * 1024 + kc * 256 + row;
            const float4* src = (const float4*)(kpk + (hb + krow) * 32 + hf * 16);
            float4 a0 = src[0], a1 = src[1];
            float4* dst = (float4*)&smem[row * 40 + hf * 16];
            dst[0] = a0; dst[1] = a1;
        }
        __syncthreads();
        #pragma unroll 4
        for (int t = 0; t < 16; t++) {
            const unsigned short* rowp = &smem[(t * 16 + n) * 40];
            bf16x8 b1 = *(const bf16x8*)(rowp + b1off);            // [Kh|Kh]
            bf16x8 b2 = {0,0,0,0,0,0,0,0};                          // [Kl|0]
            if (g < 2) b2 = *(const bf16x8*)(rowp + b2off);
            f32x4 c = {0.f, 0.f, 0.f, 0.f};
            c = __builtin_amdgcn_mfma_f32_16x16x32_bf16(afrag, b1, c, 0, 0, 0);
            c = __builtin_amdgcn_mfma_f32_16x16x32_bf16(afrag, b2, c, 0, 0, 0);
            l0 += E2(c[0]); l1 += E2(c[1]); l2 += E2(c[2]); l3 += E2(c[3]);
        }
    }
    #pragma unroll
    for (int m = 1; m < 16; m <<= 1) {
        l0 += __shfl_xor(l0, m); l1 += __shfl_xor(l1, m);
        l2 += __shfl_xor(l2, m); l3 += __shfl_xor(l3, m);
    }
    if (n == 0) {
        size_t base = (hb + q0w + g * 4) * NSLICE + ks;
        lp[base]            = l0; lp[base + NSLICE]     = l1;
        lp[base + 2*NSLICE] = l2; lp[base + 3*NSLICE]   = l3;
    }
}

// ---- 6. phase 2: column weights w_j = sum_q exp(s)/l_q; 512 thr, 128 j-rows/block ----
__global__ void __launch_bounds__(512) k_attn_w(
        const unsigned short* __restrict__ qpk, const unsigned short* __restrict__ kpk,
        const float* __restrict__ lp, float* __restrict__ wp) {
    __shared__ unsigned short smem[256 * 40];
    __shared__ float rls[256];
    int tid = threadIdx.x;
    int qs = blockIdx.x, yg = blockIdx.y, h = blockIdx.z;
    size_t hb = (size_t)h * KSEL;
    int lane = tid & 63, w = tid >> 6;
    int n = lane & 15, g = lane >> 4;
    int j0w = yg * 128 + w * 16;
    bf16x8 afrag = *(const bf16x8*)(kpk + (hb + j0w + n) * 32 + g * 8); // A=[Kh|Kl]
    float w0 = 0.f, w1 = 0.f, w2 = 0.f, w3 = 0.f;
    int b1off = (g & 1) * 8;
    int b2off = 16 + g * 8;
    for (int qc = 0; qc < 4; qc++) {
        __syncthreads();
        {
            int row = tid >> 1, hf = tid & 1;
            int qrow = qs * 1024 + qc * 256 + row;
            const float4* src = (const float4*)(qpk + (hb + qrow) * 32 + hf * 16);
            float4 a0 = src[0], a1 = src[1];
            float4* dst = (float4*)&smem[row * 40 + hf * 16];
            dst[0] = a0; dst[1] = a1;
            if (hf == 0) {
                float4 p = ((const float4*)lp)[hb + qrow];
                rls[row] = 1.0f / ((p.x + p.y) + (p.z + p.w));
            }
        }
        __syncthreads();
        #pragma unroll 4
        for (int t = 0; t < 16; t++) {
            const unsigned short* rowp = &smem[(t * 16 + n) * 40];
            bf16x8 b1 = *(const bf16x8*)(rowp + b1off);            // [Qh|Qh]
            bf16x8 b2 = {0,0,0,0,0,0,0,0};                          // [Ql|0]
            if (g < 2) b2 = *(const bf16x8*)(rowp + b2off);
            f32x4 c = {0.f, 0.f, 0.f, 0.f};
            c = __builtin_amdgcn_mfma_f32_16x16x32_bf16(afrag, b1, c, 0, 0, 0);
            c = __builtin_amdgcn_mfma_f32_16x16x32_bf16(afrag, b2, c, 0, 0, 0);
            float rv = rls[t * 16 + n];
            w0 = fmaf(E2(c[0]), rv, w0); w1 = fmaf(E2(c[1]), rv, w1);
            w2 = fmaf(E2(c[2]), rv, w2); w3 = fmaf(E2(c[3]), rv, w3);
        }
    }
    #pragma unroll
    for (int m = 1; m < 16; m <<= 1) {
        w0 += __shfl_xor(w0, m); w1 += __shfl_xor(w1, m);
        w2 += __shfl_xor(w2, m); w3 += __shfl_xor(w3, m);
    }
    if (n == 0) {
        size_t base = (hb + j0w + g * 4) * NSLICE + qs;
        wp[base]            = w0; wp[base + NSLICE]     = w1;
        wp[base + 2*NSLICE] = w2; wp[base + 3*NSLICE]   = w3;
    }
}

// ---- 7. colsum + (last block) final MLP ----
// pooled_av[d] += (1/K) sum_j w[h(d)][j] * v[j][d]; last block (device-scope
// counter + threadfence) atomic-reads pav coherently and runs out-proj + MLP.
__global__ void __launch_bounds__(256) k_colsum(const float* __restrict__ wp, const float* __restrict__ vg,
        float* __restrict__ pav, unsigned int* __restrict__ done,
        const float* __restrict__ Wo, const float* __restrict__ bo,
        const float* __restrict__ W1, const float* __restrict__ b1,
        const float* __restrict__ W2, const float* __restrict__ b2,
        float* __restrict__ out) {
    __shared__ float wl[NHEADS][32];
    __shared__ float red[128];
    __shared__ int isLast;
    int tid = threadIdx.x;
    int j0 = blockIdx.x * 32;
    {
        int h = tid >> 5, jl = tid & 31;
        float4 p = ((const float4*)wp)[(size_t)h * KSEL + j0 + jl];
        wl[h][jl] = (p.x + p.y) + (p.z + p.w);
    }
    __syncthreads();
    int d = tid & 127, g = tid >> 7;
    int h = d >> 4;
    float acc = 0.f;
    for (int jl = g * 16; jl < g * 16 + 16; jl++)
        acc = fmaf(wl[h][jl], vg[(size_t)(j0 + jl) * HIDDEN + d], acc);
    if (g == 1) red[d] = acc;
    __syncthreads();
    if (g == 0) atomicAdd(&pav[d], (acc + red[d]) * (1.0f / (float)KSEL));
    __threadfence();
    __syncthreads();
    if (tid == 0) isLast = (atomicAdd(done, 1u) == (unsigned)(KSEL / 32 - 1));
    __syncthreads();
    if (!isLast) return;
    // ---- final: out-proj + pool MLP (exactly one block reaches here) ----
    __shared__ float pv[HIDDEN];
    __shared__ float sp[HIDDEN];
    __shared__ float st[OUTD];
    if (tid < HIDDEN) pv[tid] = atomicAdd(&pav[tid], 0.0f);   // coherent read
    __syncthreads();
    if (tid < HIDDEN) {
        float a = bo[tid];
        for (int c = 0; c < HIDDEN; c++) a = fmaf(pv[c], Wo[c * HIDDEN + tid], a);
        sp[tid] = a;
    }
    __syncthreads();
    {
        float a = b1[tid];
        for (int c = 0; c < HIDDEN; c++) a = fmaf(sp[c], W1[c * OUTD + tid], a);
        st[tid] = fmaxf(a, 0.f);
    }
    __syncthreads();
    {
        float o = b2[tid];
        for (int c = 0; c < OUTD; c++) o = fmaf(st[c], W2[c * OUTD + tid], o);
        out[tid] = o;
    }
}

extern "C" void kernel_launch(void* const* d_in, const int* in_sizes, int n_in,
                              void* d_out, int out_size, void* d_ws, size_t ws_size,
                              hipStream_t stream) {
    (void)n_in; (void)out_size; (void)ws_size;
    const float* x   = (const float*)d_in[0];
    const float* pos = (const float*)d_in[1];
    const float* lig = (const float*)d_in[2];
    const float* Wn  = (const float*)d_in[3];
    const float* bn  = (const float*)d_in[4];
    const float* Wq  = (const float*)d_in[5];
    const float* bq  = (const float*)d_in[6];
    const float* Wk  = (const float*)d_in[7];
    const float* bk  = (const float*)d_in[8];
    const float* Wv  = (const float*)d_in[9];
    const float* bv  = (const float*)d_in[10];
    const float* Wo  = (const float*)d_in[11];
    const float* bo  = (const float*)d_in[12];
    const float* W1  = (const float*)d_in[13];
    const float* b1  = (const float*)d_in[14];
    const float* W2  = (const float*)d_in[15];
    const float* b2  = (const float*)d_in[16];
    int M = in_sizes[2] / 3;

    char* ws = (char*)d_ws;
    unsigned short* pa  = (unsigned short*)(ws + OFF_PA);
    unsigned short* pb  = (unsigned short*)(ws + OFF_PB);
    float*          sq  = (float*)(ws + OFF_SQ);
    float*          dl  = (float*)(ws + OFF_DL);
    int*            cnt = (int*)  (ws + OFF_CNT);
    unsigned int*   nfl = (unsigned int*)(ws + OFF_NFLAG);
    unsigned int*   flg = (unsigned int*)(ws + OFF_FLG);
    int*            sel = (int*)  (ws + OFF_SEL);
    unsigned short* qpk = (unsigned short*)(ws + OFF_QPK);
    unsigned short* kpk = (unsigned short*)(ws + OFF_KPK);
    float*          vg  = (float*)(ws + OFF_V);
    float*          lp  = (float*)(ws + OFF_LP);
    float*          wp  = (float*)(ws + OFF_WP);
    float*          pav = (float*)(ws + OFF_PAV);
    unsigned int*   ghist = (unsigned int*)(ws + OFF_GH);
    unsigned int*   gkeys = (unsigned int*)(ws + OFF_GK);

    hipLaunchKernelGGL(k_prep,     dim3(64),       dim3(256),  0, stream, pos, lig, M, pa, pb, sq, dl, pav, cnt, nfl, ghist);
    hipLaunchKernelGGL(k_neighbor, dim3(128, 16),  dim3(256),  0, stream, pa, pb, cnt, flg, nfl);
    hipLaunchKernelGGL(k_fixup,    dim3(32),       dim3(256),  0, stream, pos, sq, flg, nfl, cnt);
    hipLaunchKernelGGL(k_select,   dim3(16),       dim3(1024), 0, stream, dl, cnt, ghist, nfl + 2, gkeys, sel);
    hipLaunchKernelGGL(k_qkv,      dim3(KSEL/4),   dim3(128),  0, stream, x, sel, Wn, bn, Wq, bq, Wk, bk, Wv, bv, qpk, kpk, vg);
    hipLaunchKernelGGL(k_attn_l,   dim3(4, 32, 8), dim3(512),  0, stream, qpk, kpk, lp);
    hipLaunchKernelGGL(k_attn_w,   dim3(4, 32, 8), dim3(512),  0, stream, qpk, kpk, lp, wp);
    hipLaunchKernelGGL(k_colsum,   dim3(KSEL/32),  dim3(256),  0, stream, wp, vg, pav, nfl + 1,
                       Wo, bo, W1, b1, W2, b2, (float*)d_out);
}

// Round 13
// 258.343 us; speedup vs baseline: 1.1961x; 1.1961x over previous
//
#include <hip/hip_runtime.h>
#include <cstdint>
#include <cstddef>

#define NPTS 16384
#define KSEL 4096
#define HIDDEN 128
#define NHEADS 8
#define DHEAD 16
#define OUTD 256
#define NSLICE 4   // k/q slices for attn partials
#define FCAP 131072
#define LCAP 512
#define TAU 0.2f

typedef __attribute__((ext_vector_type(8))) short bf16x8;
typedef __attribute__((ext_vector_type(4))) float f32x4;
typedef __attribute__((ext_vector_type(16))) float f32x16;

#if defined(__has_builtin)
#if __has_builtin(__builtin_amdgcn_exp2f)
#define E2(x) __builtin_amdgcn_exp2f(x)
#endif
#endif
#ifndef E2
#define E2(x) exp2f(x)
#endif

// ---- workspace layout (bytes) ----
constexpr size_t OFF_PA    = 1024;                         // NPTS*16 bf16 (A-side packed)
constexpr size_t OFF_PB    = OFF_PA  + (size_t)NPTS*32;    // NPTS*16 bf16 (B-side packed)
constexpr size_t OFF_SQ    = OFF_PB  + (size_t)NPTS*32;
constexpr size_t OFF_DL    = OFF_SQ  + (size_t)NPTS*4;
constexpr size_t OFF_CNT   = OFF_DL  + (size_t)NPTS*4;     // int (zeroed by k_prep)
constexpr size_t OFF_NFLAG = OFF_CNT + (size_t)NPTS*4;     // uint[0]=nflag, uint[1]=done ctr
constexpr size_t OFF_FLG   = OFF_NFLAG + 1024;             // FCAP uints
constexpr size_t OFF_SEL   = OFF_FLG + (size_t)FCAP*4;     // KSEL int
constexpr size_t SZ_PK     = (size_t)NHEADS*KSEL*32*2;     // 2 MB packed [hi16|lo16] bf16
constexpr size_t OFF_QPK   = OFF_SEL + (size_t)KSEL*4;
constexpr size_t OFF_KPK   = OFF_QPK + SZ_PK;
constexpr size_t OFF_V     = OFF_KPK + SZ_PK;                      // KSEL*128 f32
constexpr size_t OFF_LP    = OFF_V  + (size_t)KSEL*HIDDEN*4;       // 8*4096*4 f32 partial l
constexpr size_t OFF_RL    = OFF_LP + (size_t)NHEADS*KSEL*NSLICE*4; // (unused, kept)
constexpr size_t OFF_WP    = OFF_RL + (size_t)NHEADS*KSEL*4;        // 8*4096*4 f32 partial w
constexpr size_t OFF_PAV   = OFF_WP + (size_t)NHEADS*KSEL*NSLICE*4; // 128 f32

__device__ __forceinline__ unsigned short f2bf(float f) {
    union { float f; unsigned u; } v; v.f = f;
    unsigned r = v.u + 0x7fffu + ((v.u >> 16) & 1u);
    return (unsigned short)(r >> 16);
}
__device__ __forceinline__ float bf2f(unsigned short h) {
    union { unsigned u; float f; } v; v.u = ((unsigned)h) << 16;
    return v.f;
}

// ---- 1. prep: ligand center, sq, d_lig, packed hi/lo coords; zeroes cnt/nflag/ctr/pav ----
// A-side s-slot carries (s - 9.0) so the neighbor MFMA emits c = d^2 - 9 directly.
__global__ void __launch_bounds__(256) k_prep(const float* __restrict__ pos, const float* __restrict__ lig, int M,
                       unsigned short* __restrict__ pa, unsigned short* __restrict__ pb,
                       float* __restrict__ sq, float* __restrict__ dl, float* __restrict__ pav,
                       int* __restrict__ cnt, unsigned int* __restrict__ nfl) {
    __shared__ float ls[128];
    __shared__ float ctr[3];
    int tid = threadIdx.x;
    if (blockIdx.x == 0) {
        if (tid < HIDDEN) pav[tid] = 0.f;
        if (tid < 2) nfl[tid] = 0;           // nflag + done-counter
    }
    for (int i = tid; i < 3 * M; i += 256) ls[i] = lig[i];
    __syncthreads();
    if (tid < 3) {
        float s = 0.f;
        for (int i = 0; i < M; i++) s += ls[i * 3 + tid];
        ctr[tid] = s / (float)M;
    }
    __syncthreads();
    int i = blockIdx.x * 256 + tid;
    cnt[i] = 0;                              // fused memset
    float x = pos[i*3+0], y = pos[i*3+1], z = pos[i*3+2];
    float s = (x*x + y*y) + z*z;
    sq[i] = s;
    float dx = x - ctr[0], dy = y - ctr[1], dz = z - ctr[2];
    dl[i] = sqrtf((dx*dx + dy*dy) + dz*dz);
    unsigned short xh = f2bf(x); float xr = bf2f(xh); float xl = x - xr;
    unsigned short yh = f2bf(y); float yr = bf2f(yh); float yl = y - yr;
    unsigned short zh = f2bf(z); float zr = bf2f(zh); float zl = z - zr;
    unsigned short xlb = f2bf(xl), ylb = f2bf(yl), zlb = f2bf(zl);
    unsigned short xhA = f2bf(-2.f*xr), xlA = f2bf(-2.f*xl);
    unsigned short yhA = f2bf(-2.f*yr), ylA = f2bf(-2.f*yl);
    unsigned short zhA = f2bf(-2.f*zr), zlA = f2bf(-2.f*zl);
    float sm9 = s - 9.0f;                      // folded threshold (A side only)
    unsigned short sihA = f2bf(sm9);
    unsigned short silA = f2bf(sm9 - bf2f(sihA));
    unsigned short sih = f2bf(s);
    unsigned short sil = f2bf(s - bf2f(sih));
    unsigned short one = f2bf(1.0f);
    union { unsigned short s[16]; float4 f[2]; } A, B;
    // k-slots: per coord (hh, h*lo_j, lo_i*h), 9-11 lo*lo, 12-13 (s_a-9)*1, 14-15 1*s_b
    A.s[0]=xhA; A.s[1]=xhA; A.s[2]=xlA;
    A.s[3]=yhA; A.s[4]=yhA; A.s[5]=ylA;
    A.s[6]=zhA; A.s[7]=zhA; A.s[8]=zlA;
    A.s[9]=xlA; A.s[10]=ylA; A.s[11]=zlA;
    A.s[12]=sihA; A.s[13]=silA; A.s[14]=one; A.s[15]=one;
    B.s[0]=xh;  B.s[1]=xlb;  B.s[2]=xh;
    B.s[3]=yh;  B.s[4]=ylb;  B.s[5]=yh;
    B.s[6]=zh;  B.s[7]=zlb;  B.s[8]=zh;
    B.s[9]=xlb; B.s[10]=ylb; B.s[11]=zlb;
    B.s[12]=one; B.s[13]=one; B.s[14]=sih; B.s[15]=sil;
    float4* pad = (float4*)(pa + (size_t)i * 16);
    pad[0] = A.f[0]; pad[1] = A.f[1];
    float4* pbd = (float4*)(pb + (size_t)i * 16);
    pbd[0] = B.f[0]; pbd[1] = B.f[1];
}

// ---- 2. neighbor counts via ONE 32x32x16 MFMA per 1024 pairs (r5 proven form) ----
__global__ void __launch_bounds__(256) k_neighbor(
        const unsigned short* __restrict__ pa, const unsigned short* __restrict__ pb,
        int* __restrict__ cnt, unsigned int* __restrict__ flg, unsigned int* __restrict__ nflag) {
    __shared__ unsigned short js[256 * 24];     // 48B row stride (16B-aligned halves)
    __shared__ unsigned int fbuf[LCAP];
    __shared__ unsigned int fcnt, fbase;
    int tid = threadIdx.x;
    if (tid == 0) fcnt = 0;
    int lane = tid & 63, w = tid >> 6;
    int half = lane >> 5, il = lane & 31;
    int i = blockIdx.x * 128 + w * 32 + il;
    bf16x8 bfrag = *(const bf16x8*)(pb + (size_t)i * 16 + half * 8);
    int jb0 = blockIdx.y * 1024;
    int acc = 0;
    const f32x16 czero = {0.f,0.f,0.f,0.f,0.f,0.f,0.f,0.f,0.f,0.f,0.f,0.f,0.f,0.f,0.f,0.f};
    for (int chv = 0; chv < 4; chv++) {
        int jb = jb0 + chv * 256;
        __syncthreads();
        {
            const float4* src = (const float4*)(pa + (size_t)(jb + tid) * 16);
            float4 v0 = src[0], v1 = src[1];
            float4* dst = (float4*)&js[tid * 24];
            dst[0] = v0; dst[1] = v1;
        }
        __syncthreads();
        #pragma unroll 2
        for (int t = 0; t < 8; t++) {
            bf16x8 afrag = *(const bf16x8*)&js[(t * 32 + il) * 24 + half * 8];
            f32x16 c = __builtin_amdgcn_mfma_f32_32x32x16_bf16(afrag, bfrag, czero, 0, 0, 0);
            int cs = 0;
            #pragma unroll
            for (int r = 0; r < 16; r++) cs += (c[r] < -TAU);
            acc += cs;
            // min |c| over the 16 columns: fires iff a window element exists
            float a0 = fminf(fabsf(c[0]),  fabsf(c[1]));
            float a1 = fminf(fabsf(c[2]),  fabsf(c[3]));
            float a2 = fminf(fabsf(c[4]),  fabsf(c[5]));
            float a3 = fminf(fabsf(c[6]),  fabsf(c[7]));
            float a4 = fminf(fabsf(c[8]),  fabsf(c[9]));
            float a5 = fminf(fabsf(c[10]), fabsf(c[11]));
            float a6 = fminf(fabsf(c[12]), fabsf(c[13]));
            float a7 = fminf(fabsf(c[14]), fabsf(c[15]));
            float b0 = fminf(a0, a1), b1 = fminf(a2, a3);
            float b2 = fminf(a4, a5), b3 = fminf(a6, a7);
            float mn = fminf(fminf(b0, b1), fminf(b2, b3));
            if (mn <= TAU) {                 // rare: boundary pair(s) in this lane's column
                int jt = jb + t * 32;
                #pragma unroll
                for (int r = 0; r < 16; r++) {
                    float d = c[r];
                    if (d >= -TAU && d < TAU) {
                        int j = jt + (r & 3) + 8 * (r >> 2) + 4 * half;
                        unsigned xx = atomicAdd(&fcnt, 1u);
                        if (xx < LCAP) fbuf[xx] = ((unsigned)i << 14) | (unsigned)j;
                    }
                }
            }
        }
    }
    acc += __shfl_xor(acc, 32);
    if (half == 0) atomicAdd(&cnt[i], acc);
    __syncthreads();
    if (tid == 0) {
        unsigned cf = fcnt; if (cf > LCAP) cf = LCAP;
        fcnt = cf;
        fbase = atomicAdd(nflag, cf);
    }
    __syncthreads();
    unsigned cf = fcnt, fb = fbase;
    for (unsigned xx = tid; xx < cf; xx += 256) {
        unsigned di = fb + xx;
        if (di < FCAP) flg[di] = fbuf[xx];
    }
}

// ---- 2b. resolve boundary-window pairs exactly (fp32) ----
__global__ void __launch_bounds__(256) k_fixup(const float* __restrict__ pos, const float* __restrict__ sq,
        const unsigned int* __restrict__ flg, const unsigned int* __restrict__ nflag,
        int* __restrict__ cnt) {
    int nf = (int)*nflag; if (nf > FCAP) nf = FCAP;
    for (int idx = blockIdx.x * 256 + threadIdx.x; idx < nf; idx += gridDim.x * 256) {
        unsigned pr = flg[idx];
        int i = (int)((pr >> 14) & 16383u), j = (int)(pr & 16383u);
        float xi = pos[i*3+0], yi = pos[i*3+1], zi = pos[i*3+2];
        float xj = pos[j*3+0], yj = pos[j*3+1], zj = pos[j*3+2];
        float dot = fmaf(xi, xj, fmaf(yi, yj, zi * zj));
        float d2 = (sq[i] + sq[j]) - 2.0f * dot;
        if (d2 < 9.0f) atomicAdd(&cnt[i], 1);
    }
}

// ---- 3. scores + exact top-KSEL radix select (hybrid-aggregation, r10 proven) ----
// Pass 0: exponent digits concentrated -> 8-ballot match-any, one atomic per
// distinct digit per wave. Passes 1-3: near-uniform -> plain atomics.
// Suffix scan: single-wave shuffle scan. Output compaction wave-aggregated.
__global__ void __launch_bounds__(1024) k_select(const float* __restrict__ dl, const int* __restrict__ cnt,
                                                 int* __restrict__ sel) {
    __shared__ unsigned int sk[NPTS];
    __shared__ int hist[256];
    __shared__ int scan2[256];
    __shared__ unsigned int s_prefix;
    __shared__ int s_rem, s_eqtot, s_nout, s_digit, s_cgt;
    int tid = threadIdx.x;
    int lane = tid & 63;
    for (int i = tid; i < NPTS; i += 1024) {
        float score = 1.0f / (1.0f + dl[i] / 5.0f) + 0.5f * (1.0f / (float)cnt[i]);
        unsigned int u = __float_as_uint(score);
        sk[i] = u ^ ((u & 0x80000000u) ? 0xFFFFFFFFu : 0x80000000u);
    }
    if (tid == 0) { s_prefix = 0; s_rem = KSEL; s_nout = 0; s_eqtot = 0; }
    __syncthreads();
    for (int p = 0; p < 4; p++) {
        int sh = 24 - 8 * p;
        if (tid < 256) hist[tid] = 0;
        __syncthreads();
        unsigned int pref = s_prefix;
        if (p == 0) {
            for (int i = tid; i < NPTS; i += 1024) {
                unsigned int dg = sk[i] >> 24;          // all lanes active
                unsigned long long mask = ~0ULL;
                #pragma unroll
                for (int b = 0; b < 8; b++) {
                    unsigned long long bb = __ballot((dg >> b) & 1u);
                    mask &= ((dg >> b) & 1u) ? bb : ~bb;
                }
                int leader = __ffsll((long long)mask) - 1;
                if (lane == leader) atomicAdd(&hist[dg], __popcll(mask));
            }
        } else {
            int shp = 32 - 8 * p;
            for (int i = tid; i < NPTS; i += 1024) {
                unsigned int key = sk[i];
                if ((key >> shp) == pref) atomicAdd(&hist[(key >> sh) & 255], 1);
            }
        }
        __syncthreads();
        // suffix scan of hist[256] within wave 0 (4 bins/lane, shuffle scan)
        if (tid < 64) {
            int h0 = hist[tid*4], h1 = hist[tid*4+1], h2 = hist[tid*4+2], h3 = hist[tid*4+3];
            int s = h0 + h1 + h2 + h3;
            #pragma unroll
            for (int off = 1; off < 64; off <<= 1) {
                int v = __shfl_down(s, off);
                if (tid + off < 64) s += v;
            }
            scan2[tid*4+0] = s;
            scan2[tid*4+1] = s - h0;
            scan2[tid*4+2] = s - h0 - h1;
            scan2[tid*4+3] = s - h0 - h1 - h2;
        }
        __syncthreads();
        int rem = s_rem;
        if (tid < 256) {
            int hi = scan2[tid];
            int lo = hi - hist[tid];
            if (hi >= rem && lo < rem) { s_digit = tid; s_cgt = lo; }
        }
        __syncthreads();
        if (tid == 0) {
            s_prefix = (s_prefix << 8) | (unsigned int)s_digit;
            s_rem = rem - s_cgt;
            if (p == 3) s_eqtot = hist[s_digit];
        }
        __syncthreads();
    }
    unsigned int T = s_prefix;
    int need_eq = s_rem;
    for (int i = tid; i < NPTS; i += 1024) {
        bool cond = (sk[i] > T);
        unsigned long long bal = __ballot(cond);
        if (bal) {
            int leader = __ffsll((long long)bal) - 1;
            int b0 = 0;
            if (lane == leader) b0 = atomicAdd(&s_nout, __popcll(bal));
            b0 = __shfl(b0, leader);
            if (cond) {
                unsigned long long lower = bal & ((1ULL << lane) - 1ULL);
                sel[b0 + __popcll(lower)] = i;
            }
        }
    }
    __syncthreads();
    if (s_eqtot == need_eq) {
        for (int i = tid; i < NPTS; i += 1024) {
            bool cond = (sk[i] == T);
            unsigned long long bal = __ballot(cond);
            if (bal) {
                int leader = __ffsll((long long)bal) - 1;
                int b0 = 0;
                if (lane == leader) b0 = atomicAdd(&s_nout, __popcll(bal));
                b0 = __shfl(b0, leader);
                if (cond) {
                    unsigned long long lower = bal & ((1ULL << lane) - 1ULL);
                    sel[b0 + __popcll(lower)] = i;
                }
            }
        }
    } else {
        for (int i = tid; i < NPTS; i += 1024) {
            if (sk[i] == T) {
                int rank = 0;
                for (int j = 0; j < i; j++) rank += (sk[j] == T);
                if (rank < need_eq) sel[atomicAdd(&s_nout, 1)] = i;
            }
        }
    }
}

// ---- 4. gather + node embed + QKV projections (4 rows/block for 2 waves/SIMD) ----
__device__ __forceinline__ void proj4(const float hs[4][HIDDEN], const float* __restrict__ W,
                                      float b, int d, float* acc) {
    #pragma unroll
    for (int r = 0; r < 4; r++) acc[r] = b;
    for (int c = 0; c < HIDDEN; c += 4) {
        float w0 = W[(c+0)*HIDDEN+d], w1 = W[(c+1)*HIDDEN+d], w2 = W[(c+2)*HIDDEN+d], w3 = W[(c+3)*HIDDEN+d];
        #pragma unroll
        for (int r = 0; r < 4; r++) {
            float4 h4 = *(const float4*)&hs[r][c];
            float a = acc[r];
            a = fmaf(h4.x, w0, a); a = fmaf(h4.y, w1, a); a = fmaf(h4.z, w2, a); a = fmaf(h4.w, w3, a);
            acc[r] = a;
        }
    }
}

__global__ void __launch_bounds__(128) k_qkv(const float* __restrict__ x, const int* __restrict__ sel,
        const float* __restrict__ Wn, const float* __restrict__ bn,
        const float* __restrict__ Wq, const float* __restrict__ bq,
        const float* __restrict__ Wk, const float* __restrict__ bk,
        const float* __restrict__ Wv, const float* __restrict__ bv,
        unsigned short* __restrict__ qpk, unsigned short* __restrict__ kpk,
        float* __restrict__ vg) {
    __shared__ float xs[4][8];
    __shared__ __align__(16) float hs[4][HIDDEN];
    int d = threadIdx.x;
    int r0 = blockIdx.x * 4;
    if (d < 32) { int rr = d >> 3, cc = d & 7; xs[rr][cc] = x[(size_t)sel[r0 + rr] * 8 + cc]; }
    __syncthreads();
    {
        float wn[8];
        #pragma unroll
        for (int c = 0; c < 8; c++) wn[c] = Wn[c * HIDDEN + d];
        float b = bn[d];
        #pragma unroll
        for (int r = 0; r < 4; r++) {
            float a = b;
            #pragma unroll
            for (int c = 0; c < 8; c++) a = fmaf(xs[r][c], wn[c], a);
            hs[r][d] = a;
        }
    }
    __syncthreads();
    int hh = d >> 4, dd = d & 15;
    float acc[4];
    // Q (pre-scaled by log2(e)/4, split hi/lo)
    proj4(hs, Wq, bq[d], d, acc);
    #pragma unroll
    for (int r = 0; r < 4; r++) {
        float val = acc[r] * 0.36067376022224085f;
        unsigned short hi = f2bf(val);
        unsigned short lo = f2bf(val - bf2f(hi));
        size_t idx = ((size_t)(hh * KSEL) + r0 + r) * 32 + dd;
        qpk[idx] = hi; qpk[idx + 16] = lo;
    }
    // K
    proj4(hs, Wk, bk[d], d, acc);
    #pragma unroll
    for (int r = 0; r < 4; r++) {
        float val = acc[r];
        unsigned short hi = f2bf(val);
        unsigned short lo = f2bf(val - bf2f(hi));
        size_t idx = ((size_t)(hh * KSEL) + r0 + r) * 32 + dd;
        kpk[idx] = hi; kpk[idx + 16] = lo;
    }
    // V (fp32, row-major [q][128])
    proj4(hs, Wv, bv[d], d, acc);
    #pragma unroll
    for (int r = 0; r < 4; r++) vg[(size_t)(r0+r)*HIDDEN + d] = acc[r];
}

// ---- 5. phase 1: row sums l_q via MFMA; 512 thr = 8 waves = 128 q-rows/block ----
__global__ void __launch_bounds__(512) k_attn_l(
        const unsigned short* __restrict__ qpk, const unsigned short* __restrict__ kpk,
        float* __restrict__ lp) {
    __shared__ unsigned short smem[256 * 40];
    int tid = threadIdx.x;
    int ks = blockIdx.x, yg = blockIdx.y, h = blockIdx.z;
    size_t hb = (size_t)h * KSEL;
    int lane = tid & 63, w = tid >> 6;      // w in 0..7
    int n = lane & 15, g = lane >> 4;
    int q0w = yg * 128 + w * 16;
    bf16x8 afrag = *(const bf16x8*)(qpk + (hb + q0w + n) * 32 + g * 8); // A=[Qh|Ql]
    float l0 = 0.f, l1 = 0.f, l2 = 0.f, l3 = 0.f;
    int b1off = (g & 1) * 8;
    int b2off = 16 + g * 8;
    for (int kc = 0; kc < 4; kc++) {
        __syncthreads();
        {
            int row = tid >> 1, hf = tid & 1;     // 2 threads per row, 32B each
            int krow = ks * 1024 + kc * 256 + row;
            const float4* src = (const float4*)(kpk + (hb + krow) * 32 + hf * 16);
            float4 a0 = src[0], a1 = src[1];
            float4* dst = (float4*)&smem[row * 40 + hf * 16];
            dst[0] = a0; dst[1] = a1;
        }
        __syncthreads();
        #pragma unroll 4
        for (int t = 0; t < 16; t++) {
            const unsigned short* rowp = &smem[(t * 16 + n) * 40];
            bf16x8 b1 = *(const bf16x8*)(rowp + b1off);            // [Kh|Kh]
            bf16x8 b2 = {0,0,0,0,0,0,0,0};                          // [Kl|0]
            if (g < 2) b2 = *(const bf16x8*)(rowp + b2off);
            f32x4 c = {0.f, 0.f, 0.f, 0.f};
            c = __builtin_amdgcn_mfma_f32_16x16x32_bf16(afrag, b1, c, 0, 0, 0);
            c = __builtin_amdgcn_mfma_f32_16x16x32_bf16(afrag, b2, c, 0, 0, 0);
            l0 += E2(c[0]); l1 += E2(c[1]); l2 += E2(c[2]); l3 += E2(c[3]);
        }
    }
    #pragma unroll
    for (int m = 1; m < 16; m <<= 1) {
        l0 += __shfl_xor(l0, m); l1 += __shfl_xor(l1, m);
        l2 += __shfl_xor(l2, m); l3 += __shfl_xor(l3, m);
    }
    if (n == 0) {
        size_t base = (hb + q0w + g * 4) * NSLICE + ks;
        lp[base]            = l0; lp[base + NSLICE]     = l1;
        lp[base + 2*NSLICE] = l2; lp[base + 3*NSLICE]   = l3;
    }
}

// ---- 6. phase 2: column weights w_j = sum_q exp(s)/l_q; 512 thr, 128 j-rows/block ----
__global__ void __launch_bounds__(512) k_attn_w(
        const unsigned short* __restrict__ qpk, const unsigned short* __restrict__ kpk,
        const float* __restrict__ lp, float* __restrict__ wp) {
    __shared__ unsigned short smem[256 * 40];
    __shared__ float rls[256];
    int tid = threadIdx.x;
    int qs = blockIdx.x, yg = blockIdx.y, h = blockIdx.z;
    size_t hb = (size_t)h * KSEL;
    int lane = tid & 63, w = tid >> 6;
    int n = lane & 15, g = lane >> 4;
    int j0w = yg * 128 + w * 16;
    bf16x8 afrag = *(const bf16x8*)(kpk + (hb + j0w + n) * 32 + g * 8); // A=[Kh|Kl]
    float w0 = 0.f, w1 = 0.f, w2 = 0.f, w3 = 0.f;
    int b1off = (g & 1) * 8;
    int b2off = 16 + g * 8;
    for (int qc = 0; qc < 4; qc++) {
        __syncthreads();
        {
            int row = tid >> 1, hf = tid & 1;
            int qrow = qs * 1024 + qc * 256 + row;
            const float4* src = (const float4*)(qpk + (hb + qrow) * 32 + hf * 16);
            float4 a0 = src[0], a1 = src[1];
            float4* dst = (float4*)&smem[row * 40 + hf * 16];
            dst[0] = a0; dst[1] = a1;
            if (hf == 0) {
                float4 p = ((const float4*)lp)[hb + qrow];
                rls[row] = 1.0f / ((p.x + p.y) + (p.z + p.w));
            }
        }
        __syncthreads();
        #pragma unroll 4
        for (int t = 0; t < 16; t++) {
            const unsigned short* rowp = &smem[(t * 16 + n) * 40];
            bf16x8 b1 = *(const bf16x8*)(rowp + b1off);            // [Qh|Qh]
            bf16x8 b2 = {0,0,0,0,0,0,0,0};                          // [Ql|0]
            if (g < 2) b2 = *(const bf16x8*)(rowp + b2off);
            f32x4 c = {0.f, 0.f, 0.f, 0.f};
            c = __builtin_amdgcn_mfma_f32_16x16x32_bf16(afrag, b1, c, 0, 0, 0);
            c = __builtin_amdgcn_mfma_f32_16x16x32_bf16(afrag, b2, c, 0, 0, 0);
            float rv = rls[t * 16 + n];
            w0 = fmaf(E2(c[0]), rv, w0); w1 = fmaf(E2(c[1]), rv, w1);
            w2 = fmaf(E2(c[2]), rv, w2); w3 = fmaf(E2(c[3]), rv, w3);
        }
    }
    #pragma unroll
    for (int m = 1; m < 16; m <<= 1) {
        w0 += __shfl_xor(w0, m); w1 += __shfl_xor(w1, m);
        w2 += __shfl_xor(w2, m); w3 += __shfl_xor(w3, m);
    }
    if (n == 0) {
        size_t base = (hb + j0w + g * 4) * NSLICE + qs;
        wp[base]            = w0; wp[base + NSLICE]     = w1;
        wp[base + 2*NSLICE] = w2; wp[base + 3*NSLICE]   = w3;
    }
}

// ---- 7. colsum + (last block) final MLP ----
// pooled_av[d] += (1/K) sum_j w[h(d)][j] * v[j][d]; last block (device-scope
// counter + threadfence) atomic-reads pav coherently and runs out-proj + MLP.
__global__ void __launch_bounds__(256) k_colsum(const float* __restrict__ wp, const float* __restrict__ vg,
        float* __restrict__ pav, unsigned int* __restrict__ done,
        const float* __restrict__ Wo, const float* __restrict__ bo,
        const float* __restrict__ W1, const float* __restrict__ b1,
        const float* __restrict__ W2, const float* __restrict__ b2,
        float* __restrict__ out) {
    __shared__ float wl[NHEADS][32];
    __shared__ float red[128];
    __shared__ int isLast;
    int tid = threadIdx.x;
    int j0 = blockIdx.x * 32;
    {
        int h = tid >> 5, jl = tid & 31;
        float4 p = ((const float4*)wp)[(size_t)h * KSEL + j0 + jl];
        wl[h][jl] = (p.x + p.y) + (p.z + p.w);
    }
    __syncthreads();
    int d = tid & 127, g = tid >> 7;
    int h = d >> 4;
    float acc = 0.f;
    for (int jl = g * 16; jl < g * 16 + 16; jl++)
        acc = fmaf(wl[h][jl], vg[(size_t)(j0 + jl) * HIDDEN + d], acc);
    if (g == 1) red[d] = acc;
    __syncthreads();
    if (g == 0) atomicAdd(&pav[d], (acc + red[d]) * (1.0f / (float)KSEL));
    __threadfence();
    __syncthreads();
    if (tid == 0) isLast = (atomicAdd(done, 1u) == (unsigned)(KSEL / 32 - 1));
    __syncthreads();
    if (!isLast) return;
    // ---- final: out-proj + pool MLP (exactly one block reaches here) ----
    __shared__ float pv[HIDDEN];
    __shared__ float sp[HIDDEN];
    __shared__ float st[OUTD];
    if (tid < HIDDEN) pv[tid] = atomicAdd(&pav[tid], 0.0f);   // coherent read
    __syncthreads();
    if (tid < HIDDEN) {
        float a = bo[tid];
        for (int c = 0; c < HIDDEN; c++) a = fmaf(pv[c], Wo[c * HIDDEN + tid], a);
        sp[tid] = a;
    }
    __syncthreads();
    {
        float a = b1[tid];
        for (int c = 0; c < HIDDEN; c++) a = fmaf(sp[c], W1[c * OUTD + tid], a);
        st[tid] = fmaxf(a, 0.f);
    }
    __syncthreads();
    {
        float o = b2[tid];
        for (int c = 0; c < OUTD; c++) o = fmaf(st[c], W2[c * OUTD + tid], o);
        out[tid] = o;
    }
}

extern "C" void kernel_launch(void* const* d_in, const int* in_sizes, int n_in,
                              void* d_out, int out_size, void* d_ws, size_t ws_size,
                              hipStream_t stream) {
    (void)n_in; (void)out_size; (void)ws_size;
    const float* x   = (const float*)d_in[0];
    const float* pos = (const float*)d_in[1];
    const float* lig = (const float*)d_in[2];
    const float* Wn  = (const float*)d_in[3];
    const float* bn  = (const float*)d_in[4];
    const float* Wq  = (const float*)d_in[5];
    const float* bq  = (const float*)d_in[6];
    const float* Wk  = (const float*)d_in[7];
    const float* bk  = (const float*)d_in[8];
    const float* Wv  = (const float*)d_in[9];
    const float* bv  = (const float*)d_in[10];
    const float* Wo  = (const float*)d_in[11];
    const float* bo  = (const float*)d_in[12];
    const float* W1  = (const float*)d_in[13];
    const float* b1  = (const float*)d_in[14];
    const float* W2  = (const float*)d_in[15];
    const float* b2  = (const float*)d_in[16];
    int M = in_sizes[2] / 3;

    char* ws = (char*)d_ws;
    unsigned short* pa  = (unsigned short*)(ws + OFF_PA);
    unsigned short* pb  = (unsigned short*)(ws + OFF_PB);
    float*          sq  = (float*)(ws + OFF_SQ);
    float*          dl  = (float*)(ws + OFF_DL);
    int*            cnt = (int*)  (ws + OFF_CNT);
    unsigned int*   nfl = (unsigned int*)(ws + OFF_NFLAG);
    unsigned int*   flg = (unsigned int*)(ws + OFF_FLG);
    int*            sel = (int*)  (ws + OFF_SEL);
    unsigned short* qpk = (unsigned short*)(ws + OFF_QPK);
    unsigned short* kpk = (unsigned short*)(ws + OFF_KPK);
    float*          vg  = (float*)(ws + OFF_V);
    float*          lp  = (float*)(ws + OFF_LP);
    float*          wp  = (float*)(ws + OFF_WP);
    float*          pav = (float*)(ws + OFF_PAV);

    hipLaunchKernelGGL(k_prep,     dim3(64),       dim3(256),  0, stream, pos, lig, M, pa, pb, sq, dl, pav, cnt, nfl);
    hipLaunchKernelGGL(k_neighbor, dim3(128, 16),  dim3(256),  0, stream, pa, pb, cnt, flg, nfl);
    hipLaunchKernelGGL(k_fixup,    dim3(32),       dim3(256),  0, stream, pos, sq, flg, nfl, cnt);
    hipLaunchKernelGGL(k_select,   dim3(1),        dim3(1024), 0, stream, dl, cnt, sel);
    hipLaunchKernelGGL(k_qkv,      dim3(KSEL/4),   dim3(128),  0, stream, x, sel, Wn, bn, Wq, bq, Wk, bk, Wv, bv, qpk, kpk, vg);
    hipLaunchKernelGGL(k_attn_l,   dim3(4, 32, 8), dim3(512),  0, stream, qpk, kpk, lp);
    hipLaunchKernelGGL(k_attn_w,   dim3(4, 32, 8), dim3(512),  0, stream, qpk, kpk, lp, wp);
    hipLaunchKernelGGL(k_colsum,   dim3(KSEL/32),  dim3(256),  0, stream, wp, vg, pav, nfl + 1,
                       Wo, bo, W1, b1, W2, b2, (float*)d_out);
}

// Round 14
// 257.165 us; speedup vs baseline: 1.2016x; 1.0046x over previous
//
#include <hip/hip_runtime.h>
#include <cstdint>
#include <cstddef>

#define NPTS 16384
#define KSEL 4096
#define HIDDEN 128
#define NHEADS 8
#define DHEAD 16
#define OUTD 256
#define NSLICE 4   // k/q slices for attn partials
#define FCAP 131072
#define LCAP 512
#define TAU 0.2f

typedef __attribute__((ext_vector_type(8))) short bf16x8;
typedef __attribute__((ext_vector_type(4))) float f32x4;
typedef __attribute__((ext_vector_type(16))) float f32x16;

#if defined(__has_builtin)
#if __has_builtin(__builtin_amdgcn_exp2f)
#define E2(x) __builtin_amdgcn_exp2f(x)
#endif
#endif
#ifndef E2
#define E2(x) exp2f(x)
#endif

// ---- workspace layout (bytes) ----
constexpr size_t OFF_PA    = 1024;                         // NPTS*16 bf16 (A-side packed)
constexpr size_t OFF_PB    = OFF_PA  + (size_t)NPTS*32;    // NPTS*16 bf16 (B-side packed)
constexpr size_t OFF_SQ    = OFF_PB  + (size_t)NPTS*32;
constexpr size_t OFF_DL    = OFF_SQ  + (size_t)NPTS*4;
constexpr size_t OFF_CNT   = OFF_DL  + (size_t)NPTS*4;     // int (zeroed by k_prep)
constexpr size_t OFF_NFLAG = OFF_CNT + (size_t)NPTS*4;     // uint[0]=nflag, uint[1]=done ctr
constexpr size_t OFF_FLG   = OFF_NFLAG + 1024;             // FCAP uints
constexpr size_t OFF_SEL   = OFF_FLG + (size_t)FCAP*4;     // KSEL int
constexpr size_t SZ_PK     = (size_t)NHEADS*KSEL*32*2;     // 2 MB packed [hi16|lo16] bf16
constexpr size_t OFF_QPK   = OFF_SEL + (size_t)KSEL*4;
constexpr size_t OFF_KPK   = OFF_QPK + SZ_PK;
constexpr size_t OFF_V     = OFF_KPK + SZ_PK;                      // KSEL*128 f32
constexpr size_t OFF_LP    = OFF_V  + (size_t)KSEL*HIDDEN*4;       // 8*4096*4 f32 partial l
constexpr size_t OFF_RL    = OFF_LP + (size_t)NHEADS*KSEL*NSLICE*4; // (unused, kept)
constexpr size_t OFF_WP    = OFF_RL + (size_t)NHEADS*KSEL*4;        // 8*4096*4 f32 partial w
constexpr size_t OFF_PAV   = OFF_WP + (size_t)NHEADS*KSEL*NSLICE*4; // 128 f32

__device__ __forceinline__ unsigned short f2bf(float f) {
    union { float f; unsigned u; } v; v.f = f;
    unsigned r = v.u + 0x7fffu + ((v.u >> 16) & 1u);
    return (unsigned short)(r >> 16);
}
__device__ __forceinline__ float bf2f(unsigned short h) {
    union { unsigned u; float f; } v; v.u = ((unsigned)h) << 16;
    return v.f;
}

// ---- 1. prep: ligand center, sq, d_lig, packed hi/lo coords; zeroes cnt/nflag/ctr/pav ----
// A-side s-slot carries (s - 9.0) so the neighbor MFMA emits c = d^2 - 9 directly.
__global__ void __launch_bounds__(256) k_prep(const float* __restrict__ pos, const float* __restrict__ lig, int M,
                       unsigned short* __restrict__ pa, unsigned short* __restrict__ pb,
                       float* __restrict__ sq, float* __restrict__ dl, float* __restrict__ pav,
                       int* __restrict__ cnt, unsigned int* __restrict__ nfl) {
    __shared__ float ls[128];
    __shared__ float ctr[3];
    int tid = threadIdx.x;
    if (blockIdx.x == 0) {
        if (tid < HIDDEN) pav[tid] = 0.f;
        if (tid < 2) nfl[tid] = 0;           // nflag + done-counter
    }
    for (int i = tid; i < 3 * M; i += 256) ls[i] = lig[i];
    __syncthreads();
    if (tid < 3) {
        float s = 0.f;
        for (int i = 0; i < M; i++) s += ls[i * 3 + tid];
        ctr[tid] = s / (float)M;
    }
    __syncthreads();
    int i = blockIdx.x * 256 + tid;
    cnt[i] = 0;                              // fused memset
    float x = pos[i*3+0], y = pos[i*3+1], z = pos[i*3+2];
    float s = (x*x + y*y) + z*z;
    sq[i] = s;
    float dx = x - ctr[0], dy = y - ctr[1], dz = z - ctr[2];
    dl[i] = sqrtf((dx*dx + dy*dy) + dz*dz);
    unsigned short xh = f2bf(x); float xr = bf2f(xh); float xl = x - xr;
    unsigned short yh = f2bf(y); float yr = bf2f(yh); float yl = y - yr;
    unsigned short zh = f2bf(z); float zr = bf2f(zh); float zl = z - zr;
    unsigned short xlb = f2bf(xl), ylb = f2bf(yl), zlb = f2bf(zl);
    unsigned short xhA = f2bf(-2.f*xr), xlA = f2bf(-2.f*xl);
    unsigned short yhA = f2bf(-2.f*yr), ylA = f2bf(-2.f*yl);
    unsigned short zhA = f2bf(-2.f*zr), zlA = f2bf(-2.f*zl);
    float sm9 = s - 9.0f;                      // folded threshold (A side only)
    unsigned short sihA = f2bf(sm9);
    unsigned short silA = f2bf(sm9 - bf2f(sihA));
    unsigned short sih = f2bf(s);
    unsigned short sil = f2bf(s - bf2f(sih));
    unsigned short one = f2bf(1.0f);
    union { unsigned short s[16]; float4 f[2]; } A, B;
    // k-slots: per coord (hh, h*lo_j, lo_i*h), 9-11 lo*lo, 12-13 (s_a-9)*1, 14-15 1*s_b
    A.s[0]=xhA; A.s[1]=xhA; A.s[2]=xlA;
    A.s[3]=yhA; A.s[4]=yhA; A.s[5]=ylA;
    A.s[6]=zhA; A.s[7]=zhA; A.s[8]=zlA;
    A.s[9]=xlA; A.s[10]=ylA; A.s[11]=zlA;
    A.s[12]=sihA; A.s[13]=silA; A.s[14]=one; A.s[15]=one;
    B.s[0]=xh;  B.s[1]=xlb;  B.s[2]=xh;
    B.s[3]=yh;  B.s[4]=ylb;  B.s[5]=yh;
    B.s[6]=zh;  B.s[7]=zlb;  B.s[8]=zh;
    B.s[9]=xlb; B.s[10]=ylb; B.s[11]=zlb;
    B.s[12]=one; B.s[13]=one; B.s[14]=sih; B.s[15]=sil;
    float4* pad = (float4*)(pa + (size_t)i * 16);
    pad[0] = A.f[0]; pad[1] = A.f[1];
    float4* pbd = (float4*)(pb + (size_t)i * 16);
    pbd[0] = B.f[0]; pbd[1] = B.f[1];
}

// ---- 2. neighbor counts via ONE 32x32x16 MFMA per 1024 pairs (r5 proven form) ----
__global__ void __launch_bounds__(256) k_neighbor(
        const unsigned short* __restrict__ pa, const unsigned short* __restrict__ pb,
        int* __restrict__ cnt, unsigned int* __restrict__ flg, unsigned int* __restrict__ nflag) {
    __shared__ unsigned short js[256 * 24];     // 48B row stride (16B-aligned halves)
    __shared__ unsigned int fbuf[LCAP];
    __shared__ unsigned int fcnt, fbase;
    int tid = threadIdx.x;
    if (tid == 0) fcnt = 0;
    int lane = tid & 63, w = tid >> 6;
    int half = lane >> 5, il = lane & 31;
    int i = blockIdx.x * 128 + w * 32 + il;
    bf16x8 bfrag = *(const bf16x8*)(pb + (size_t)i * 16 + half * 8);
    int jb0 = blockIdx.y * 1024;
    int acc = 0;
    const f32x16 czero = {0.f,0.f,0.f,0.f,0.f,0.f,0.f,0.f,0.f,0.f,0.f,0.f,0.f,0.f,0.f,0.f};
    for (int chv = 0; chv < 4; chv++) {
        int jb = jb0 + chv * 256;
        __syncthreads();
        {
            const float4* src = (const float4*)(pa + (size_t)(jb + tid) * 16);
            float4 v0 = src[0], v1 = src[1];
            float4* dst = (float4*)&js[tid * 24];
            dst[0] = v0; dst[1] = v1;
        }
        __syncthreads();
        #pragma unroll 2
        for (int t = 0; t < 8; t++) {
            bf16x8 afrag = *(const bf16x8*)&js[(t * 32 + il) * 24 + half * 8];
            f32x16 c = __builtin_amdgcn_mfma_f32_32x32x16_bf16(afrag, bfrag, czero, 0, 0, 0);
            int cs = 0;
            #pragma unroll
            for (int r = 0; r < 16; r++) cs += (c[r] < -TAU);
            acc += cs;
            // min |c| over the 16 columns: fires iff a window element exists
            float a0 = fminf(fabsf(c[0]),  fabsf(c[1]));
            float a1 = fminf(fabsf(c[2]),  fabsf(c[3]));
            float a2 = fminf(fabsf(c[4]),  fabsf(c[5]));
            float a3 = fminf(fabsf(c[6]),  fabsf(c[7]));
            float a4 = fminf(fabsf(c[8]),  fabsf(c[9]));
            float a5 = fminf(fabsf(c[10]), fabsf(c[11]));
            float a6 = fminf(fabsf(c[12]), fabsf(c[13]));
            float a7 = fminf(fabsf(c[14]), fabsf(c[15]));
            float b0 = fminf(a0, a1), b1 = fminf(a2, a3);
            float b2 = fminf(a4, a5), b3 = fminf(a6, a7);
            float mn = fminf(fminf(b0, b1), fminf(b2, b3));
            if (mn <= TAU) {                 // rare: boundary pair(s) in this lane's column
                int jt = jb + t * 32;
                #pragma unroll
                for (int r = 0; r < 16; r++) {
                    float d = c[r];
                    if (d >= -TAU && d < TAU) {
                        int j = jt + (r & 3) + 8 * (r >> 2) + 4 * half;
                        unsigned xx = atomicAdd(&fcnt, 1u);
                        if (xx < LCAP) fbuf[xx] = ((unsigned)i << 14) | (unsigned)j;
                    }
                }
            }
        }
    }
    acc += __shfl_xor(acc, 32);
    if (half == 0) atomicAdd(&cnt[i], acc);
    __syncthreads();
    if (tid == 0) {
        unsigned cf = fcnt; if (cf > LCAP) cf = LCAP;
        fcnt = cf;
        fbase = atomicAdd(nflag, cf);
    }
    __syncthreads();
    unsigned cf = fcnt, fb = fbase;
    for (unsigned xx = tid; xx < cf; xx += 256) {
        unsigned di = fb + xx;
        if (di < FCAP) flg[di] = fbuf[xx];
    }
}

// ---- 2b. resolve boundary-window pairs exactly (fp32) ----
__global__ void __launch_bounds__(256) k_fixup(const float* __restrict__ pos, const float* __restrict__ sq,
        const unsigned int* __restrict__ flg, const unsigned int* __restrict__ nflag,
        int* __restrict__ cnt) {
    int nf = (int)*nflag; if (nf > FCAP) nf = FCAP;
    for (int idx = blockIdx.x * 256 + threadIdx.x; idx < nf; idx += gridDim.x * 256) {
        unsigned pr = flg[idx];
        int i = (int)((pr >> 14) & 16383u), j = (int)(pr & 16383u);
        float xi = pos[i*3+0], yi = pos[i*3+1], zi = pos[i*3+2];
        float xj = pos[j*3+0], yj = pos[j*3+1], zj = pos[j*3+2];
        float dot = fmaf(xi, xj, fmaf(yi, yj, zi * zj));
        float d2 = (sq[i] + sq[j]) - 2.0f * dot;
        if (d2 < 9.0f) atomicAdd(&cnt[i], 1);
    }
}

// ---- 3. scores + exact top-KSEL radix select (hybrid-aggregation, r10 proven) ----
// Pass 0: exponent digits concentrated -> 8-ballot match-any, one atomic per
// distinct digit per wave. Passes 1-3: near-uniform -> plain atomics.
// Suffix scan: single-wave shuffle scan. Output compaction wave-aggregated.
__global__ void __launch_bounds__(1024) k_select(const float* __restrict__ dl, const int* __restrict__ cnt,
                                                 int* __restrict__ sel) {
    __shared__ unsigned int sk[NPTS];
    __shared__ int hist[256];
    __shared__ int scan2[256];
    __shared__ unsigned int s_prefix;
    __shared__ int s_rem, s_eqtot, s_nout, s_digit, s_cgt;
    int tid = threadIdx.x;
    int lane = tid & 63;
    for (int i = tid; i < NPTS; i += 1024) {
        float score = 1.0f / (1.0f + dl[i] / 5.0f) + 0.5f * (1.0f / (float)cnt[i]);
        unsigned int u = __float_as_uint(score);
        sk[i] = u ^ ((u & 0x80000000u) ? 0xFFFFFFFFu : 0x80000000u);
    }
    if (tid == 0) { s_prefix = 0; s_rem = KSEL; s_nout = 0; s_eqtot = 0; }
    __syncthreads();
    for (int p = 0; p < 4; p++) {
        int sh = 24 - 8 * p;
        if (tid < 256) hist[tid] = 0;
        __syncthreads();
        unsigned int pref = s_prefix;
        if (p == 0) {
            for (int i = tid; i < NPTS; i += 1024) {
                unsigned int dg = sk[i] >> 24;          // all lanes active
                unsigned long long mask = ~0ULL;
                #pragma unroll
                for (int b = 0; b < 8; b++) {
                    unsigned long long bb = __ballot((dg >> b) & 1u);
                    mask &= ((dg >> b) & 1u) ? bb : ~bb;
                }
                int leader = __ffsll((long long)mask) - 1;
                if (lane == leader) atomicAdd(&hist[dg], __popcll(mask));
            }
        } else {
            int shp = 32 - 8 * p;
            for (int i = tid; i < NPTS; i += 1024) {
                unsigned int key = sk[i];
                if ((key >> shp) == pref) atomicAdd(&hist[(key >> sh) & 255], 1);
            }
        }
        __syncthreads();
        // suffix scan of hist[256] within wave 0 (4 bins/lane, shuffle scan)
        if (tid < 64) {
            int h0 = hist[tid*4], h1 = hist[tid*4+1], h2 = hist[tid*4+2], h3 = hist[tid*4+3];
            int s = h0 + h1 + h2 + h3;
            #pragma unroll
            for (int off = 1; off < 64; off <<= 1) {
                int v = __shfl_down(s, off);
                if (tid + off < 64) s += v;
            }
            scan2[tid*4+0] = s;
            scan2[tid*4+1] = s - h0;
            scan2[tid*4+2] = s - h0 - h1;
            scan2[tid*4+3] = s - h0 - h1 - h2;
        }
        __syncthreads();
        int rem = s_rem;
        if (tid < 256) {
            int hi = scan2[tid];
            int lo = hi - hist[tid];
            if (hi >= rem && lo < rem) { s_digit = tid; s_cgt = lo; }
        }
        __syncthreads();
        if (tid == 0) {
            s_prefix = (s_prefix << 8) | (unsigned int)s_digit;
            s_rem = rem - s_cgt;
            if (p == 3) s_eqtot = hist[s_digit];
        }
        __syncthreads();
    }
    unsigned int T = s_prefix;
    int need_eq = s_rem;
    for (int i = tid; i < NPTS; i += 1024) {
        bool cond = (sk[i] > T);
        unsigned long long bal = __ballot(cond);
        if (bal) {
            int leader = __ffsll((long long)bal) - 1;
            int b0 = 0;
            if (lane == leader) b0 = atomicAdd(&s_nout, __popcll(bal));
            b0 = __shfl(b0, leader);
            if (cond) {
                unsigned long long lower = bal & ((1ULL << lane) - 1ULL);
                sel[b0 + __popcll(lower)] = i;
            }
        }
    }
    __syncthreads();
    if (s_eqtot == need_eq) {
        for (int i = tid; i < NPTS; i += 1024) {
            bool cond = (sk[i] == T);
            unsigned long long bal = __ballot(cond);
            if (bal) {
                int leader = __ffsll((long long)bal) - 1;
                int b0 = 0;
                if (lane == leader) b0 = atomicAdd(&s_nout, __popcll(bal));
                b0 = __shfl(b0, leader);
                if (cond) {
                    unsigned long long lower = bal & ((1ULL << lane) - 1ULL);
                    sel[b0 + __popcll(lower)] = i;
                }
            }
        }
    } else {
        for (int i = tid; i < NPTS; i += 1024) {
            if (sk[i] == T) {
                int rank = 0;
                for (int j = 0; j < i; j++) rank += (sk[j] == T);
                if (rank < need_eq) sel[atomicAdd(&s_nout, 1)] = i;
            }
        }
    }
}

// ---- 4. gather + node embed + QKV projections (4 rows/block for 2 waves/SIMD) ----
__device__ __forceinline__ void proj4(const float hs[4][HIDDEN], const float* __restrict__ W,
                                      float b, int d, float* acc) {
    #pragma unroll
    for (int r = 0; r < 4; r++) acc[r] = b;
    for (int c = 0; c < HIDDEN; c += 4) {
        float w0 = W[(c+0)*HIDDEN+d], w1 = W[(c+1)*HIDDEN+d], w2 = W[(c+2)*HIDDEN+d], w3 = W[(c+3)*HIDDEN+d];
        #pragma unroll
        for (int r = 0; r < 4; r++) {
            float4 h4 = *(const float4*)&hs[r][c];
            float a = acc[r];
            a = fmaf(h4.x, w0, a); a = fmaf(h4.y, w1, a); a = fmaf(h4.z, w2, a); a = fmaf(h4.w, w3, a);
            acc[r] = a;
        }
    }
}

__global__ void __launch_bounds__(128) k_qkv(const float* __restrict__ x, const int* __restrict__ sel,
        const float* __restrict__ Wn, const float* __restrict__ bn,
        const float* __restrict__ Wq, const float* __restrict__ bq,
        const float* __restrict__ Wk, const float* __restrict__ bk,
        const float* __restrict__ Wv, const float* __restrict__ bv,
        unsigned short* __restrict__ qpk, unsigned short* __restrict__ kpk,
        float* __restrict__ vg) {
    __shared__ float xs[4][8];
    __shared__ __align__(16) float hs[4][HIDDEN];
    int d = threadIdx.x;
    int r0 = blockIdx.x * 4;
    if (d < 32) { int rr = d >> 3, cc = d & 7; xs[rr][cc] = x[(size_t)sel[r0 + rr] * 8 + cc]; }
    __syncthreads();
    {
        float wn[8];
        #pragma unroll
        for (int c = 0; c < 8; c++) wn[c] = Wn[c * HIDDEN + d];
        float b = bn[d];
        #pragma unroll
        for (int r = 0; r < 4; r++) {
            float a = b;
            #pragma unroll
            for (int c = 0; c < 8; c++) a = fmaf(xs[r][c], wn[c], a);
            hs[r][d] = a;
        }
    }
    __syncthreads();
    int hh = d >> 4, dd = d & 15;
    float acc[4];
    // Q (pre-scaled by log2(e)/4, split hi/lo)
    proj4(hs, Wq, bq[d], d, acc);
    #pragma unroll
    for (int r = 0; r < 4; r++) {
        float val = acc[r] * 0.36067376022224085f;
        unsigned short hi = f2bf(val);
        unsigned short lo = f2bf(val - bf2f(hi));
        size_t idx = ((size_t)(hh * KSEL) + r0 + r) * 32 + dd;
        qpk[idx] = hi; qpk[idx + 16] = lo;
    }
    // K
    proj4(hs, Wk, bk[d], d, acc);
    #pragma unroll
    for (int r = 0; r < 4; r++) {
        float val = acc[r];
        unsigned short hi = f2bf(val);
        unsigned short lo = f2bf(val - bf2f(hi));
        size_t idx = ((size_t)(hh * KSEL) + r0 + r) * 32 + dd;
        kpk[idx] = hi; kpk[idx + 16] = lo;
    }
    // V (fp32, row-major [q][128])
    proj4(hs, Wv, bv[d], d, acc);
    #pragma unroll
    for (int r = 0; r < 4; r++) vg[(size_t)(r0+r)*HIDDEN + d] = acc[r];
}

// ---- 5. phase 1: row sums l_q via MFMA; 1024 thr = 16 waves = 256 q-rows/block ----
// Each staged 256-row k-chunk feeds 2x the MFMA work vs the 512-thr version
// (r4->r5 widening precedent): staging traffic + barriers per unit work halved.
// grid (4,16,8) = 512 blocks = 2/CU x 16 waves = 32 waves/CU, one full round.
__global__ void __launch_bounds__(1024) k_attn_l(
        const unsigned short* __restrict__ qpk, const unsigned short* __restrict__ kpk,
        float* __restrict__ lp) {
    __shared__ unsigned short smem[256 * 40];
    int tid = threadIdx.x;
    int ks = blockIdx.x, yg = blockIdx.y, h = blockIdx.z;
    size_t hb = (size_t)h * KSEL;
    int lane = tid & 63, w = tid >> 6;      // w in 0..15
    int n = lane & 15, g = lane >> 4;
    int q0w = yg * 256 + w * 16;
    bf16x8 afrag = *(const bf16x8*)(qpk + (hb + q0w + n) * 32 + g * 8); // A=[Qh|Ql]
    float l0 = 0.f, l1 = 0.f, l2 = 0.f, l3 = 0.f;
    int b1off = (g & 1) * 8;
    int b2off = 16 + g * 8;
    for (int kc = 0; kc < 4; kc++) {
        __syncthreads();
        {
            int row = tid >> 2, hf = tid & 3;     // 4 threads per row, 16B each
            int krow = ks * 1024 + kc * 256 + row;
            float4 a0 = *(const float4*)(kpk + (hb + krow) * 32 + hf * 8);
            *(float4*)&smem[row * 40 + hf * 8] = a0;
        }
        __syncthreads();
        #pragma unroll 4
        for (int t = 0; t < 16; t++) {
            const unsigned short* rowp = &smem[(t * 16 + n) * 40];
            bf16x8 b1 = *(const bf16x8*)(rowp + b1off);            // [Kh|Kh]
            bf16x8 b2 = {0,0,0,0,0,0,0,0};                          // [Kl|0]
            if (g < 2) b2 = *(const bf16x8*)(rowp + b2off);
            f32x4 c = {0.f, 0.f, 0.f, 0.f};
            c = __builtin_amdgcn_mfma_f32_16x16x32_bf16(afrag, b1, c, 0, 0, 0);
            c = __builtin_amdgcn_mfma_f32_16x16x32_bf16(afrag, b2, c, 0, 0, 0);
            l0 += E2(c[0]); l1 += E2(c[1]); l2 += E2(c[2]); l3 += E2(c[3]);
        }
    }
    #pragma unroll
    for (int m = 1; m < 16; m <<= 1) {
        l0 += __shfl_xor(l0, m); l1 += __shfl_xor(l1, m);
        l2 += __shfl_xor(l2, m); l3 += __shfl_xor(l3, m);
    }
    if (n == 0) {
        size_t base = (hb + q0w + g * 4) * NSLICE + ks;
        lp[base]            = l0; lp[base + NSLICE]     = l1;
        lp[base + 2*NSLICE] = l2; lp[base + 3*NSLICE]   = l3;
    }
}

// ---- 6. phase 2: column weights w_j = sum_q exp(s)/l_q; 1024 thr, 256 j-rows/block ----
__global__ void __launch_bounds__(1024) k_attn_w(
        const unsigned short* __restrict__ qpk, const unsigned short* __restrict__ kpk,
        const float* __restrict__ lp, float* __restrict__ wp) {
    __shared__ unsigned short smem[256 * 40];
    __shared__ float rls[256];
    int tid = threadIdx.x;
    int qs = blockIdx.x, yg = blockIdx.y, h = blockIdx.z;
    size_t hb = (size_t)h * KSEL;
    int lane = tid & 63, w = tid >> 6;
    int n = lane & 15, g = lane >> 4;
    int j0w = yg * 256 + w * 16;
    bf16x8 afrag = *(const bf16x8*)(kpk + (hb + j0w + n) * 32 + g * 8); // A=[Kh|Kl]
    float w0 = 0.f, w1 = 0.f, w2 = 0.f, w3 = 0.f;
    int b1off = (g & 1) * 8;
    int b2off = 16 + g * 8;
    for (int qc = 0; qc < 4; qc++) {
        __syncthreads();
        {
            int row = tid >> 2, hf = tid & 3;     // 4 threads per row, 16B each
            int qrow = qs * 1024 + qc * 256 + row;
            float4 a0 = *(const float4*)(qpk + (hb + qrow) * 32 + hf * 8);
            *(float4*)&smem[row * 40 + hf * 8] = a0;
            if (hf == 0) {
                float4 p = ((const float4*)lp)[hb + qrow];
                rls[row] = 1.0f / ((p.x + p.y) + (p.z + p.w));
            }
        }
        __syncthreads();
        #pragma unroll 4
        for (int t = 0; t < 16; t++) {
            const unsigned short* rowp = &smem[(t * 16 + n) * 40];
            bf16x8 b1 = *(const bf16x8*)(rowp + b1off);            // [Qh|Qh]
            bf16x8 b2 = {0,0,0,0,0,0,0,0};                          // [Ql|0]
            if (g < 2) b2 = *(const bf16x8*)(rowp + b2off);
            f32x4 c = {0.f, 0.f, 0.f, 0.f};
            c = __builtin_amdgcn_mfma_f32_16x16x32_bf16(afrag, b1, c, 0, 0, 0);
            c = __builtin_amdgcn_mfma_f32_16x16x32_bf16(afrag, b2, c, 0, 0, 0);
            float rv = rls[t * 16 + n];
            w0 = fmaf(E2(c[0]), rv, w0); w1 = fmaf(E2(c[1]), rv, w1);
            w2 = fmaf(E2(c[2]), rv, w2); w3 = fmaf(E2(c[3]), rv, w3);
        }
    }
    #pragma unroll
    for (int m = 1; m < 16; m <<= 1) {
        w0 += __shfl_xor(w0, m); w1 += __shfl_xor(w1, m);
        w2 += __shfl_xor(w2, m); w3 += __shfl_xor(w3, m);
    }
    if (n == 0) {
        size_t base = (hb + j0w + g * 4) * NSLICE + qs;
        wp[base]            = w0; wp[base + NSLICE]     = w1;
        wp[base + 2*NSLICE] = w2; wp[base + 3*NSLICE]   = w3;
    }
}

// ---- 7. colsum + (last block) final MLP ----
// pooled_av[d] += (1/K) sum_j w[h(d)][j] * v[j][d]; last block (device-scope
// counter + threadfence) atomic-reads pav coherently and runs out-proj + MLP.
__global__ void __launch_bounds__(256) k_colsum(const float* __restrict__ wp, const float* __restrict__ vg,
        float* __restrict__ pav, unsigned int* __restrict__ done,
        const float* __restrict__ Wo, const float* __restrict__ bo,
        const float* __restrict__ W1, const float* __restrict__ b1,
        const float* __restrict__ W2, const float* __restrict__ b2,
        float* __restrict__ out) {
    __shared__ float wl[NHEADS][32];
    __shared__ float red[128];
    __shared__ int isLast;
    int tid = threadIdx.x;
    int j0 = blockIdx.x * 32;
    {
        int h = tid >> 5, jl = tid & 31;
        float4 p = ((const float4*)wp)[(size_t)h * KSEL + j0 + jl];
        wl[h][jl] = (p.x + p.y) + (p.z + p.w);
    }
    __syncthreads();
    int d = tid & 127, g = tid >> 7;
    int h = d >> 4;
    float acc = 0.f;
    for (int jl = g * 16; jl < g * 16 + 16; jl++)
        acc = fmaf(wl[h][jl], vg[(size_t)(j0 + jl) * HIDDEN + d], acc);
    if (g == 1) red[d] = acc;
    __syncthreads();
    if (g == 0) atomicAdd(&pav[d], (acc + red[d]) * (1.0f / (float)KSEL));
    __threadfence();
    __syncthreads();
    if (tid == 0) isLast = (atomicAdd(done, 1u) == (unsigned)(KSEL / 32 - 1));
    __syncthreads();
    if (!isLast) return;
    // ---- final: out-proj + pool MLP (exactly one block reaches here) ----
    __shared__ float pv[HIDDEN];
    __shared__ float sp[HIDDEN];
    __shared__ float st[OUTD];
    if (tid < HIDDEN) pv[tid] = atomicAdd(&pav[tid], 0.0f);   // coherent read
    __syncthreads();
    if (tid < HIDDEN) {
        float a = bo[tid];
        for (int c = 0; c < HIDDEN; c++) a = fmaf(pv[c], Wo[c * HIDDEN + tid], a);
        sp[tid] = a;
    }
    __syncthreads();
    {
        float a = b1[tid];
        for (int c = 0; c < HIDDEN; c++) a = fmaf(sp[c], W1[c * OUTD + tid], a);
        st[tid] = fmaxf(a, 0.f);
    }
    __syncthreads();
    {
        float o = b2[tid];
        for (int c = 0; c < OUTD; c++) o = fmaf(st[c], W2[c * OUTD + tid], o);
        out[tid] = o;
    }
}

extern "C" void kernel_launch(void* const* d_in, const int* in_sizes, int n_in,
                              void* d_out, int out_size, void* d_ws, size_t ws_size,
                              hipStream_t stream) {
    (void)n_in; (void)out_size; (void)ws_size;
    const float* x   = (const float*)d_in[0];
    const float* pos = (const float*)d_in[1];
    const float* lig = (const float*)d_in[2];
    const float* Wn  = (const float*)d_in[3];
    const float* bn  = (const float*)d_in[4];
    const float* Wq  = (const float*)d_in[5];
    const float* bq  = (const float*)d_in[6];
    const float* Wk  = (const float*)d_in[7];
    const float* bk  = (const float*)d_in[8];
    const float* Wv  = (const float*)d_in[9];
    const float* bv  = (const float*)d_in[10];
    const float* Wo  = (const float*)d_in[11];
    const float* bo  = (const float*)d_in[12];
    const float* W1  = (const float*)d_in[13];
    const float* b1  = (const float*)d_in[14];
    const float* W2  = (const float*)d_in[15];
    const float* b2  = (const float*)d_in[16];
    int M = in_sizes[2] / 3;

    char* ws = (char*)d_ws;
    unsigned short* pa  = (unsigned short*)(ws + OFF_PA);
    unsigned short* pb  = (unsigned short*)(ws + OFF_PB);
    float*          sq  = (float*)(ws + OFF_SQ);
    float*          dl  = (float*)(ws + OFF_DL);
    int*            cnt = (int*)  (ws + OFF_CNT);
    unsigned int*   nfl = (unsigned int*)(ws + OFF_NFLAG);
    unsigned int*   flg = (unsigned int*)(ws + OFF_FLG);
    int*            sel = (int*)  (ws + OFF_SEL);
    unsigned short* qpk = (unsigned short*)(ws + OFF_QPK);
    unsigned short* kpk = (unsigned short*)(ws + OFF_KPK);
    float*          vg  = (float*)(ws + OFF_V);
    float*          lp  = (float*)(ws + OFF_LP);
    float*          wp  = (float*)(ws + OFF_WP);
    float*          pav = (float*)(ws + OFF_PAV);

    hipLaunchKernelGGL(k_prep,     dim3(64),       dim3(256),  0, stream, pos, lig, M, pa, pb, sq, dl, pav, cnt, nfl);
    hipLaunchKernelGGL(k_neighbor, dim3(128, 16),  dim3(256),  0, stream, pa, pb, cnt, flg, nfl);
    hipLaunchKernelGGL(k_fixup,    dim3(32),       dim3(256),  0, stream, pos, sq, flg, nfl, cnt);
    hipLaunchKernelGGL(k_select,   dim3(1),        dim3(1024), 0, stream, dl, cnt, sel);
    hipLaunchKernelGGL(k_qkv,      dim3(KSEL/4),   dim3(128),  0, stream, x, sel, Wn, bn, Wq, bq, Wk, bk, Wv, bv, qpk, kpk, vg);
    hipLaunchKernelGGL(k_attn_l,   dim3(4, 16, 8), dim3(1024), 0, stream, qpk, kpk, lp);
    hipLaunchKernelGGL(k_attn_w,   dim3(4, 16, 8), dim3(1024), 0, stream, qpk, kpk, lp, wp);
    hipLaunchKernelGGL(k_colsum,   dim3(KSEL/32),  dim3(256),  0, stream, wp, vg, pav, nfl + 1,
                       Wo, bo, W1, b1, W2, b2, (float*)d_out);
}

// Round 15
// 246.591 us; speedup vs baseline: 1.2531x; 1.0429x over previous
//
#include <hip/hip_runtime.h>
#include <cstdint>
#include <cstddef>

#define NPTS 16384
#define KSEL 4096
#define HIDDEN 128
#define NHEADS 8
#define DHEAD 16
#define OUTD 256
#define NSLICE 4   // k/q slices for attn partials
#define FCAP 131072
#define LCAP 512
#define TAU 0.2f

typedef __attribute__((ext_vector_type(8))) short bf16x8;
typedef __attribute__((ext_vector_type(4))) float f32x4;
typedef __attribute__((ext_vector_type(16))) float f32x16;

#if defined(__has_builtin)
#if __has_builtin(__builtin_amdgcn_exp2f)
#define E2(x) __builtin_amdgcn_exp2f(x)
#endif
#endif
#ifndef E2
#define E2(x) exp2f(x)
#endif

// ---- workspace layout (bytes) ----
constexpr size_t OFF_PA    = 1024;                         // NPTS*16 bf16 (A-side packed)
constexpr size_t OFF_PB    = OFF_PA  + (size_t)NPTS*32;    // NPTS*16 bf16 (B-side packed)
constexpr size_t OFF_SQ    = OFF_PB  + (size_t)NPTS*32;
constexpr size_t OFF_DL    = OFF_SQ  + (size_t)NPTS*4;
constexpr size_t OFF_CNT   = OFF_DL  + (size_t)NPTS*4;     // int (zeroed by k_prep)
constexpr size_t OFF_NFLAG = OFF_CNT + (size_t)NPTS*4;     // uint[0]=nflag, uint[1]=done ctr
constexpr size_t OFF_FLG   = OFF_NFLAG + 1024;             // FCAP uints
constexpr size_t OFF_SEL   = OFF_FLG + (size_t)FCAP*4;     // KSEL int
constexpr size_t SZ_PK     = (size_t)NHEADS*KSEL*32*2;     // 2 MB packed [hi16|lo16] bf16
constexpr size_t OFF_QPK   = OFF_SEL + (size_t)KSEL*4;
constexpr size_t OFF_KPK   = OFF_QPK + SZ_PK;
constexpr size_t OFF_V     = OFF_KPK + SZ_PK;                      // KSEL*128 f32
constexpr size_t OFF_LP    = OFF_V  + (size_t)KSEL*HIDDEN*4;       // 8*4096*4 f32 partial l
constexpr size_t OFF_RL    = OFF_LP + (size_t)NHEADS*KSEL*NSLICE*4; // (unused, kept)
constexpr size_t OFF_WP    = OFF_RL + (size_t)NHEADS*KSEL*4;        // 8*4096*4 f32 partial w
constexpr size_t OFF_PAV   = OFF_WP + (size_t)NHEADS*KSEL*NSLICE*4; // 128 f32

__device__ __forceinline__ unsigned short f2bf(float f) {
    union { float f; unsigned u; } v; v.f = f;
    unsigned r = v.u + 0x7fffu + ((v.u >> 16) & 1u);
    return (unsigned short)(r >> 16);
}
__device__ __forceinline__ float bf2f(unsigned short h) {
    union { unsigned u; float f; } v; v.u = ((unsigned)h) << 16;
    return v.f;
}

// ---- 1. prep: ligand center, sq, d_lig, packed hi/lo coords; zeroes cnt/nflag/ctr/pav ----
// A-side s-slot carries (s - 9.0) so the neighbor MFMA emits c = d^2 - 9 directly.
__global__ void __launch_bounds__(256) k_prep(const float* __restrict__ pos, const float* __restrict__ lig, int M,
                       unsigned short* __restrict__ pa, unsigned short* __restrict__ pb,
                       float* __restrict__ sq, float* __restrict__ dl, float* __restrict__ pav,
                       int* __restrict__ cnt, unsigned int* __restrict__ nfl) {
    __shared__ float ls[128];
    __shared__ float ctr[3];
    int tid = threadIdx.x;
    if (blockIdx.x == 0) {
        if (tid < HIDDEN) pav[tid] = 0.f;
        if (tid < 2) nfl[tid] = 0;           // nflag + done-counter
    }
    for (int i = tid; i < 3 * M; i += 256) ls[i] = lig[i];
    __syncthreads();
    if (tid < 3) {
        float s = 0.f;
        for (int i = 0; i < M; i++) s += ls[i * 3 + tid];
        ctr[tid] = s / (float)M;
    }
    __syncthreads();
    int i = blockIdx.x * 256 + tid;
    cnt[i] = 0;                              // fused memset
    float x = pos[i*3+0], y = pos[i*3+1], z = pos[i*3+2];
    float s = (x*x + y*y) + z*z;
    sq[i] = s;
    float dx = x - ctr[0], dy = y - ctr[1], dz = z - ctr[2];
    dl[i] = sqrtf((dx*dx + dy*dy) + dz*dz);
    unsigned short xh = f2bf(x); float xr = bf2f(xh); float xl = x - xr;
    unsigned short yh = f2bf(y); float yr = bf2f(yh); float yl = y - yr;
    unsigned short zh = f2bf(z); float zr = bf2f(zh); float zl = z - zr;
    unsigned short xlb = f2bf(xl), ylb = f2bf(yl), zlb = f2bf(zl);
    unsigned short xhA = f2bf(-2.f*xr), xlA = f2bf(-2.f*xl);
    unsigned short yhA = f2bf(-2.f*yr), ylA = f2bf(-2.f*yl);
    unsigned short zhA = f2bf(-2.f*zr), zlA = f2bf(-2.f*zl);
    float sm9 = s - 9.0f;                      // folded threshold (A side only)
    unsigned short sihA = f2bf(sm9);
    unsigned short silA = f2bf(sm9 - bf2f(sihA));
    unsigned short sih = f2bf(s);
    unsigned short sil = f2bf(s - bf2f(sih));
    unsigned short one = f2bf(1.0f);
    union { unsigned short s[16]; float4 f[2]; } A, B;
    // k-slots: per coord (hh, h*lo_j, lo_i*h), 9-11 lo*lo, 12-13 (s_a-9)*1, 14-15 1*s_b
    A.s[0]=xhA; A.s[1]=xhA; A.s[2]=xlA;
    A.s[3]=yhA; A.s[4]=yhA; A.s[5]=ylA;
    A.s[6]=zhA; A.s[7]=zhA; A.s[8]=zlA;
    A.s[9]=xlA; A.s[10]=ylA; A.s[11]=zlA;
    A.s[12]=sihA; A.s[13]=silA; A.s[14]=one; A.s[15]=one;
    B.s[0]=xh;  B.s[1]=xlb;  B.s[2]=xh;
    B.s[3]=yh;  B.s[4]=ylb;  B.s[5]=yh;
    B.s[6]=zh;  B.s[7]=zlb;  B.s[8]=zh;
    B.s[9]=xlb; B.s[10]=ylb; B.s[11]=zlb;
    B.s[12]=one; B.s[13]=one; B.s[14]=sih; B.s[15]=sil;
    float4* pad = (float4*)(pa + (size_t)i * 16);
    pad[0] = A.f[0]; pad[1] = A.f[1];
    float4* pbd = (float4*)(pb + (size_t)i * 16);
    pbd[0] = B.f[0]; pbd[1] = B.f[1];
}

// ---- 2. neighbor counts via ONE 32x32x16 MFMA per 1024 pairs ----
// WIDENED (r5 attn precedent): 512 thr = 8 waves x 32 i-rows = 256 i/block.
// Each staged 256-row j-chunk feeds 2x the MFMA work -> staging insts +
// barrier count per unit pair-work halved. grid (64,16) = 1024 blocks =
// 4/CU x 8 waves = 32 waves/CU (occupancy-neutral), one full round.
__global__ void __launch_bounds__(512) k_neighbor(
        const unsigned short* __restrict__ pa, const unsigned short* __restrict__ pb,
        int* __restrict__ cnt, unsigned int* __restrict__ flg, unsigned int* __restrict__ nflag) {
    __shared__ unsigned short js[256 * 24];     // 48B row stride (16B-aligned halves)
    __shared__ unsigned int fbuf[LCAP];
    __shared__ unsigned int fcnt, fbase;
    int tid = threadIdx.x;
    if (tid == 0) fcnt = 0;
    int lane = tid & 63, w = tid >> 6;          // w in 0..7
    int half = lane >> 5, il = lane & 31;
    int i = blockIdx.x * 256 + w * 32 + il;
    bf16x8 bfrag = *(const bf16x8*)(pb + (size_t)i * 16 + half * 8);
    int jb0 = blockIdx.y * 1024;
    int acc = 0;
    const f32x16 czero = {0.f,0.f,0.f,0.f,0.f,0.f,0.f,0.f,0.f,0.f,0.f,0.f,0.f,0.f,0.f,0.f};
    for (int chv = 0; chv < 4; chv++) {
        int jb = jb0 + chv * 256;
        __syncthreads();
        {
            int row = tid >> 1, hf = tid & 1;   // 2 threads per row, 16B each
            float4 v0 = *(const float4*)(pa + (size_t)(jb + row) * 16 + hf * 8);
            *(float4*)&js[row * 24 + hf * 8] = v0;
        }
        __syncthreads();
        #pragma unroll 2
        for (int t = 0; t < 8; t++) {
            bf16x8 afrag = *(const bf16x8*)&js[(t * 32 + il) * 24 + half * 8];
            f32x16 c = __builtin_amdgcn_mfma_f32_32x32x16_bf16(afrag, bfrag, czero, 0, 0, 0);
            int cs = 0;
            #pragma unroll
            for (int r = 0; r < 16; r++) cs += (c[r] < -TAU);
            acc += cs;
            // min |c| over the 16 columns: fires iff a window element exists
            float a0 = fminf(fabsf(c[0]),  fabsf(c[1]));
            float a1 = fminf(fabsf(c[2]),  fabsf(c[3]));
            float a2 = fminf(fabsf(c[4]),  fabsf(c[5]));
            float a3 = fminf(fabsf(c[6]),  fabsf(c[7]));
            float a4 = fminf(fabsf(c[8]),  fabsf(c[9]));
            float a5 = fminf(fabsf(c[10]), fabsf(c[11]));
            float a6 = fminf(fabsf(c[12]), fabsf(c[13]));
            float a7 = fminf(fabsf(c[14]), fabsf(c[15]));
            float b0 = fminf(a0, a1), b1 = fminf(a2, a3);
            float b2 = fminf(a4, a5), b3 = fminf(a6, a7);
            float mn = fminf(fminf(b0, b1), fminf(b2, b3));
            if (mn <= TAU) {                 // rare: boundary pair(s) in this lane's column
                int jt = jb + t * 32;
                #pragma unroll
                for (int r = 0; r < 16; r++) {
                    float d = c[r];
                    if (d >= -TAU && d < TAU) {
                        int j = jt + (r & 3) + 8 * (r >> 2) + 4 * half;
                        unsigned xx = atomicAdd(&fcnt, 1u);
                        if (xx < LCAP) fbuf[xx] = ((unsigned)i << 14) | (unsigned)j;
                    }
                }
            }
        }
    }
    acc += __shfl_xor(acc, 32);
    if (half == 0) atomicAdd(&cnt[i], acc);
    __syncthreads();
    if (tid == 0) {
        unsigned cf = fcnt; if (cf > LCAP) cf = LCAP;
        fcnt = cf;
        fbase = atomicAdd(nflag, cf);
    }
    __syncthreads();
    unsigned cf = fcnt, fb = fbase;
    for (unsigned xx = tid; xx < cf; xx += 512) {
        unsigned di = fb + xx;
        if (di < FCAP) flg[di] = fbuf[xx];
    }
}

// ---- 2b. resolve boundary-window pairs exactly (fp32) ----
__global__ void __launch_bounds__(256) k_fixup(const float* __restrict__ pos, const float* __restrict__ sq,
        const unsigned int* __restrict__ flg, const unsigned int* __restrict__ nflag,
        int* __restrict__ cnt) {
    int nf = (int)*nflag; if (nf > FCAP) nf = FCAP;
    for (int idx = blockIdx.x * 256 + threadIdx.x; idx < nf; idx += gridDim.x * 256) {
        unsigned pr = flg[idx];
        int i = (int)((pr >> 14) & 16383u), j = (int)(pr & 16383u);
        float xi = pos[i*3+0], yi = pos[i*3+1], zi = pos[i*3+2];
        float xj = pos[j*3+0], yj = pos[j*3+1], zj = pos[j*3+2];
        float dot = fmaf(xi, xj, fmaf(yi, yj, zi * zj));
        float d2 = (sq[i] + sq[j]) - 2.0f * dot;
        if (d2 < 9.0f) atomicAdd(&cnt[i], 1);
    }
}

// ---- 3. scores + exact top-KSEL radix select (hybrid-aggregation, r10 proven) ----
__global__ void __launch_bounds__(1024) k_select(const float* __restrict__ dl, const int* __restrict__ cnt,
                                                 int* __restrict__ sel) {
    __shared__ unsigned int sk[NPTS];
    __shared__ int hist[256];
    __shared__ int scan2[256];
    __shared__ unsigned int s_prefix;
    __shared__ int s_rem, s_eqtot, s_nout, s_digit, s_cgt;
    int tid = threadIdx.x;
    int lane = tid & 63;
    for (int i = tid; i < NPTS; i += 1024) {
        float score = 1.0f / (1.0f + dl[i] / 5.0f) + 0.5f * (1.0f / (float)cnt[i]);
        unsigned int u = __float_as_uint(score);
        sk[i] = u ^ ((u & 0x80000000u) ? 0xFFFFFFFFu : 0x80000000u);
    }
    if (tid == 0) { s_prefix = 0; s_rem = KSEL; s_nout = 0; s_eqtot = 0; }
    __syncthreads();
    for (int p = 0; p < 4; p++) {
        int sh = 24 - 8 * p;
        if (tid < 256) hist[tid] = 0;
        __syncthreads();
        unsigned int pref = s_prefix;
        if (p == 0) {
            for (int i = tid; i < NPTS; i += 1024) {
                unsigned int dg = sk[i] >> 24;          // all lanes active
                unsigned long long mask = ~0ULL;
                #pragma unroll
                for (int b = 0; b < 8; b++) {
                    unsigned long long bb = __ballot((dg >> b) & 1u);
                    mask &= ((dg >> b) & 1u) ? bb : ~bb;
                }
                int leader = __ffsll((long long)mask) - 1;
                if (lane == leader) atomicAdd(&hist[dg], __popcll(mask));
            }
        } else {
            int shp = 32 - 8 * p;
            for (int i = tid; i < NPTS; i += 1024) {
                unsigned int key = sk[i];
                if ((key >> shp) == pref) atomicAdd(&hist[(key >> sh) & 255], 1);
            }
        }
        __syncthreads();
        // suffix scan of hist[256] within wave 0 (4 bins/lane, shuffle scan)
        if (tid < 64) {
            int h0 = hist[tid*4], h1 = hist[tid*4+1], h2 = hist[tid*4+2], h3 = hist[tid*4+3];
            int s = h0 + h1 + h2 + h3;
            #pragma unroll
            for (int off = 1; off < 64; off <<= 1) {
                int v = __shfl_down(s, off);
                if (tid + off < 64) s += v;
            }
            scan2[tid*4+0] = s;
            scan2[tid*4+1] = s - h0;
            scan2[tid*4+2] = s - h0 - h1;
            scan2[tid*4+3] = s - h0 - h1 - h2;
        }
        __syncthreads();
        int rem = s_rem;
        if (tid < 256) {
            int hi = scan2[tid];
            int lo = hi - hist[tid];
            if (hi >= rem && lo < rem) { s_digit = tid; s_cgt = lo; }
        }
        __syncthreads();
        if (tid == 0) {
            s_prefix = (s_prefix << 8) | (unsigned int)s_digit;
            s_rem = rem - s_cgt;
            if (p == 3) s_eqtot = hist[s_digit];
        }
        __syncthreads();
    }
    unsigned int T = s_prefix;
    int need_eq = s_rem;
    for (int i = tid; i < NPTS; i += 1024) {
        bool cond = (sk[i] > T);
        unsigned long long bal = __ballot(cond);
        if (bal) {
            int leader = __ffsll((long long)bal) - 1;
            int b0 = 0;
            if (lane == leader) b0 = atomicAdd(&s_nout, __popcll(bal));
            b0 = __shfl(b0, leader);
            if (cond) {
                unsigned long long lower = bal & ((1ULL << lane) - 1ULL);
                sel[b0 + __popcll(lower)] = i;
            }
        }
    }
    __syncthreads();
    if (s_eqtot == need_eq) {
        for (int i = tid; i < NPTS; i += 1024) {
            bool cond = (sk[i] == T);
            unsigned long long bal = __ballot(cond);
            if (bal) {
                int leader = __ffsll((long long)bal) - 1;
                int b0 = 0;
                if (lane == leader) b0 = atomicAdd(&s_nout, __popcll(bal));
                b0 = __shfl(b0, leader);
                if (cond) {
                    unsigned long long lower = bal & ((1ULL << lane) - 1ULL);
                    sel[b0 + __popcll(lower)] = i;
                }
            }
        }
    } else {
        for (int i = tid; i < NPTS; i += 1024) {
            if (sk[i] == T) {
                int rank = 0;
                for (int j = 0; j < i; j++) rank += (sk[j] == T);
                if (rank < need_eq) sel[atomicAdd(&s_nout, 1)] = i;
            }
        }
    }
}

// ---- 4. gather + node embed + QKV projections (4 rows/block for 2 waves/SIMD) ----
__device__ __forceinline__ void proj4(const float hs[4][HIDDEN], const float* __restrict__ W,
                                      float b, int d, float* acc) {
    #pragma unroll
    for (int r = 0; r < 4; r++) acc[r] = b;
    for (int c = 0; c < HIDDEN; c += 4) {
        float w0 = W[(c+0)*HIDDEN+d], w1 = W[(c+1)*HIDDEN+d], w2 = W[(c+2)*HIDDEN+d], w3 = W[(c+3)*HIDDEN+d];
        #pragma unroll
        for (int r = 0; r < 4; r++) {
            float4 h4 = *(const float4*)&hs[r][c];
            float a = acc[r];
            a = fmaf(h4.x, w0, a); a = fmaf(h4.y, w1, a); a = fmaf(h4.z, w2, a); a = fmaf(h4.w, w3, a);
            acc[r] = a;
        }
    }
}

__global__ void __launch_bounds__(128) k_qkv(const float* __restrict__ x, const int* __restrict__ sel,
        const float* __restrict__ Wn, const float* __restrict__ bn,
        const float* __restrict__ Wq, const float* __restrict__ bq,
        const float* __restrict__ Wk, const float* __restrict__ bk,
        const float* __restrict__ Wv, const float* __restrict__ bv,
        unsigned short* __restrict__ qpk, unsigned short* __restrict__ kpk,
        float* __restrict__ vg) {
    __shared__ float xs[4][8];
    __shared__ __align__(16) float hs[4][HIDDEN];
    int d = threadIdx.x;
    int r0 = blockIdx.x * 4;
    if (d < 32) { int rr = d >> 3, cc = d & 7; xs[rr][cc] = x[(size_t)sel[r0 + rr] * 8 + cc]; }
    __syncthreads();
    {
        float wn[8];
        #pragma unroll
        for (int c = 0; c < 8; c++) wn[c] = Wn[c * HIDDEN + d];
        float b = bn[d];
        #pragma unroll
        for (int r = 0; r < 4; r++) {
            float a = b;
            #pragma unroll
            for (int c = 0; c < 8; c++) a = fmaf(xs[r][c], wn[c], a);
            hs[r][d] = a;
        }
    }
    __syncthreads();
    int hh = d >> 4, dd = d & 15;
    float acc[4];
    // Q (pre-scaled by log2(e)/4, split hi/lo)
    proj4(hs, Wq, bq[d], d, acc);
    #pragma unroll
    for (int r = 0; r < 4; r++) {
        float val = acc[r] * 0.36067376022224085f;
        unsigned short hi = f2bf(val);
        unsigned short lo = f2bf(val - bf2f(hi));
        size_t idx = ((size_t)(hh * KSEL) + r0 + r) * 32 + dd;
        qpk[idx] = hi; qpk[idx + 16] = lo;
    }
    // K
    proj4(hs, Wk, bk[d], d, acc);
    #pragma unroll
    for (int r = 0; r < 4; r++) {
        float val = acc[r];
        unsigned short hi = f2bf(val);
        unsigned short lo = f2bf(val - bf2f(hi));
        size_t idx = ((size_t)(hh * KSEL) + r0 + r) * 32 + dd;
        kpk[idx] = hi; kpk[idx + 16] = lo;
    }
    // V (fp32, row-major [q][128])
    proj4(hs, Wv, bv[d], d, acc);
    #pragma unroll
    for (int r = 0; r < 4; r++) vg[(size_t)(r0+r)*HIDDEN + d] = acc[r];
}

// ---- 5. phase 1: row sums l_q via MFMA; 1024 thr = 16 waves = 256 q-rows/block ----
__global__ void __launch_bounds__(1024) k_attn_l(
        const unsigned short* __restrict__ qpk, const unsigned short* __restrict__ kpk,
        float* __restrict__ lp) {
    __shared__ unsigned short smem[256 * 40];
    int tid = threadIdx.x;
    int ks = blockIdx.x, yg = blockIdx.y, h = blockIdx.z;
    size_t hb = (size_t)h * KSEL;
    int lane = tid & 63, w = tid >> 6;      // w in 0..15
    int n = lane & 15, g = lane >> 4;
    int q0w = yg * 256 + w * 16;
    bf16x8 afrag = *(const bf16x8*)(qpk + (hb + q0w + n) * 32 + g * 8); // A=[Qh|Ql]
    float l0 = 0.f, l1 = 0.f, l2 = 0.f, l3 = 0.f;
    int b1off = (g & 1) * 8;
    int b2off = 16 + g * 8;
    for (int kc = 0; kc < 4; kc++) {
        __syncthreads();
        {
            int row = tid >> 2, hf = tid & 3;     // 4 threads per row, 16B each
            int krow = ks * 1024 + kc * 256 + row;
            float4 a0 = *(const float4*)(kpk + (hb + krow) * 32 + hf * 8);
            *(float4*)&smem[row * 40 + hf * 8] = a0;
        }
        __syncthreads();
        #pragma unroll 4
        for (int t = 0; t < 16; t++) {
            const unsigned short* rowp = &smem[(t * 16 + n) * 40];
            bf16x8 b1 = *(const bf16x8*)(rowp + b1off);            // [Kh|Kh]
            bf16x8 b2 = {0,0,0,0,0,0,0,0};                          // [Kl|0]
            if (g < 2) b2 = *(const bf16x8*)(rowp + b2off);
            f32x4 c = {0.f, 0.f, 0.f, 0.f};
            c = __builtin_amdgcn_mfma_f32_16x16x32_bf16(afrag, b1, c, 0, 0, 0);
            c = __builtin_amdgcn_mfma_f32_16x16x32_bf16(afrag, b2, c, 0, 0, 0);
            l0 += E2(c[0]); l1 += E2(c[1]); l2 += E2(c[2]); l3 += E2(c[3]);
        }
    }
    #pragma unroll
    for (int m = 1; m < 16; m <<= 1) {
        l0 += __shfl_xor(l0, m); l1 += __shfl_xor(l1, m);
        l2 += __shfl_xor(l2, m); l3 += __shfl_xor(l3, m);
    }
    if (n == 0) {
        size_t base = (hb + q0w + g * 4) * NSLICE + ks;
        lp[base]            = l0; lp[base + NSLICE]     = l1;
        lp[base + 2*NSLICE] = l2; lp[base + 3*NSLICE]   = l3;
    }
}

// ---- 6. phase 2: column weights w_j = sum_q exp(s)/l_q; 1024 thr, 256 j-rows/block ----
__global__ void __launch_bounds__(1024) k_attn_w(
        const unsigned short* __restrict__ qpk, const unsigned short* __restrict__ kpk,
        const float* __restrict__ lp, float* __restrict__ wp) {
    __shared__ unsigned short smem[256 * 40];
    __shared__ float rls[256];
    int tid = threadIdx.x;
    int qs = blockIdx.x, yg = blockIdx.y, h = blockIdx.z;
    size_t hb = (size_t)h * KSEL;
    int lane = tid & 63, w = tid >> 6;
    int n = lane & 15, g = lane >> 4;
    int j0w = yg * 256 + w * 16;
    bf16x8 afrag = *(const bf16x8*)(kpk + (hb + j0w + n) * 32 + g * 8); // A=[Kh|Kl]
    float w0 = 0.f, w1 = 0.f, w2 = 0.f, w3 = 0.f;
    int b1off = (g & 1) * 8;
    int b2off = 16 + g * 8;
    for (int qc = 0; qc < 4; qc++) {
        __syncthreads();
        {
            int row = tid >> 2, hf = tid & 3;     // 4 threads per row, 16B each
            int qrow = qs * 1024 + qc * 256 + row;
            float4 a0 = *(const float4*)(qpk + (hb + qrow) * 32 + hf * 8);
            *(float4*)&smem[row * 40 + hf * 8] = a0;
            if (hf == 0) {
                float4 p = ((const float4*)lp)[hb + qrow];
                rls[row] = 1.0f / ((p.x + p.y) + (p.z + p.w));
            }
        }
        __syncthreads();
        #pragma unroll 4
        for (int t = 0; t < 16; t++) {
            const unsigned short* rowp = &smem[(t * 16 + n) * 40];
            bf16x8 b1 = *(const bf16x8*)(rowp + b1off);            // [Qh|Qh]
            bf16x8 b2 = {0,0,0,0,0,0,0,0};                          // [Ql|0]
            if (g < 2) b2 = *(const bf16x8*)(rowp + b2off);
            f32x4 c = {0.f, 0.f, 0.f, 0.f};
            c = __builtin_amdgcn_mfma_f32_16x16x32_bf16(afrag, b1, c, 0, 0, 0);
            c = __builtin_amdgcn_mfma_f32_16x16x32_bf16(afrag, b2, c, 0, 0, 0);
            float rv = rls[t * 16 + n];
            w0 = fmaf(E2(c[0]), rv, w0); w1 = fmaf(E2(c[1]), rv, w1);
            w2 = fmaf(E2(c[2]), rv, w2); w3 = fmaf(E2(c[3]), rv, w3);
        }
    }
    #pragma unroll
    for (int m = 1; m < 16; m <<= 1) {
        w0 += __shfl_xor(w0, m); w1 += __shfl_xor(w1, m);
        w2 += __shfl_xor(w2, m); w3 += __shfl_xor(w3, m);
    }
    if (n == 0) {
        size_t base = (hb + j0w + g * 4) * NSLICE + qs;
        wp[base]            = w0; wp[base + NSLICE]     = w1;
        wp[base + 2*NSLICE] = w2; wp[base + 3*NSLICE]   = w3;
    }
}

// ---- 7. colsum + (last block) final MLP ----
__global__ void __launch_bounds__(256) k_colsum(const float* __restrict__ wp, const float* __restrict__ vg,
        float* __restrict__ pav, unsigned int* __restrict__ done,
        const float* __restrict__ Wo, const float* __restrict__ bo,
        const float* __restrict__ W1, const float* __restrict__ b1,
        const float* __restrict__ W2, const float* __restrict__ b2,
        float* __restrict__ out) {
    __shared__ float wl[NHEADS][32];
    __shared__ float red[128];
    __shared__ int isLast;
    int tid = threadIdx.x;
    int j0 = blockIdx.x * 32;
    {
        int h = tid >> 5, jl = tid & 31;
        float4 p = ((const float4*)wp)[(size_t)h * KSEL + j0 + jl];
        wl[h][jl] = (p.x + p.y) + (p.z + p.w);
    }
    __syncthreads();
    int d = tid & 127, g = tid >> 7;
    int h = d >> 4;
    float acc = 0.f;
    for (int jl = g * 16; jl < g * 16 + 16; jl++)
        acc = fmaf(wl[h][jl], vg[(size_t)(j0 + jl) * HIDDEN + d], acc);
    if (g == 1) red[d] = acc;
    __syncthreads();
    if (g == 0) atomicAdd(&pav[d], (acc + red[d]) * (1.0f / (float)KSEL));
    __threadfence();
    __syncthreads();
    if (tid == 0) isLast = (atomicAdd(done, 1u) == (unsigned)(KSEL / 32 - 1));
    __syncthreads();
    if (!isLast) return;
    // ---- final: out-proj + pool MLP (exactly one block reaches here) ----
    __shared__ float pv[HIDDEN];
    __shared__ float sp[HIDDEN];
    __shared__ float st[OUTD];
    if (tid < HIDDEN) pv[tid] = atomicAdd(&pav[tid], 0.0f);   // coherent read
    __syncthreads();
    if (tid < HIDDEN) {
        float a = bo[tid];
        for (int c = 0; c < HIDDEN; c++) a = fmaf(pv[c], Wo[c * HIDDEN + tid], a);
        sp[tid] = a;
    }
    __syncthreads();
    {
        float a = b1[tid];
        for (int c = 0; c < HIDDEN; c++) a = fmaf(sp[c], W1[c * OUTD + tid], a);
        st[tid] = fmaxf(a, 0.f);
    }
    __syncthreads();
    {
        float o = b2[tid];
        for (int c = 0; c < OUTD; c++) o = fmaf(st[c], W2[c * OUTD + tid], o);
        out[tid] = o;
    }
}

extern "C" void kernel_launch(void* const* d_in, const int* in_sizes, int n_in,
                              void* d_out, int out_size, void* d_ws, size_t ws_size,
                              hipStream_t stream) {
    (void)n_in; (void)out_size; (void)ws_size;
    const float* x   = (const float*)d_in[0];
    const float* pos = (const float*)d_in[1];
    const float* lig = (const float*)d_in[2];
    const float* Wn  = (const float*)d_in[3];
    const float* bn  = (const float*)d_in[4];
    const float* Wq  = (const float*)d_in[5];
    const float* bq  = (const float*)d_in[6];
    const float* Wk  = (const float*)d_in[7];
    const float* bk  = (const float*)d_in[8];
    const float* Wv  = (const float*)d_in[9];
    const float* bv  = (const float*)d_in[10];
    const float* Wo  = (const float*)d_in[11];
    const float* bo  = (const float*)d_in[12];
    const float* W1  = (const float*)d_in[13];
    const float* b1  = (const float*)d_in[14];
    const float* W2  = (const float*)d_in[15];
    const float* b2  = (const float*)d_in[16];
    int M = in_sizes[2] / 3;

    char* ws = (char*)d_ws;
    unsigned short* pa  = (unsigned short*)(ws + OFF_PA);
    unsigned short* pb  = (unsigned short*)(ws + OFF_PB);
    float*          sq  = (float*)(ws + OFF_SQ);
    float*          dl  = (float*)(ws + OFF_DL);
    int*            cnt = (int*)  (ws + OFF_CNT);
    unsigned int*   nfl = (unsigned int*)(ws + OFF_NFLAG);
    unsigned int*   flg = (unsigned int*)(ws + OFF_FLG);
    int*            sel = (int*)  (ws + OFF_SEL);
    unsigned short* qpk = (unsigned short*)(ws + OFF_QPK);
    unsigned short* kpk = (unsigned short*)(ws + OFF_KPK);
    float*          vg  = (float*)(ws + OFF_V);
    float*          lp  = (float*)(ws + OFF_LP);
    float*          wp  = (float*)(ws + OFF_WP);
    float*          pav = (float*)(ws + OFF_PAV);

    hipLaunchKernelGGL(k_prep,     dim3(64),       dim3(256),  0, stream, pos, lig, M, pa, pb, sq, dl, pav, cnt, nfl);
    hipLaunchKernelGGL(k_neighbor, dim3(64, 16),   dim3(512),  0, stream, pa, pb, cnt, flg, nfl);
    hipLaunchKernelGGL(k_fixup,    dim3(32),       dim3(256),  0, stream, pos, sq, flg, nfl, cnt);
    hipLaunchKernelGGL(k_select,   dim3(1),        dim3(1024), 0, stream, dl, cnt, sel);
    hipLaunchKernelGGL(k_qkv,      dim3(KSEL/4),   dim3(128),  0, stream, x, sel, Wn, bn, Wq, bq, Wk, bk, Wv, bv, qpk, kpk, vg);
    hipLaunchKernelGGL(k_attn_l,   dim3(4, 16, 8), dim3(1024), 0, stream, qpk, kpk, lp);
    hipLaunchKernelGGL(k_attn_w,   dim3(4, 16, 8), dim3(1024), 0, stream, qpk, kpk, lp, wp);
    hipLaunchKernelGGL(k_colsum,   dim3(KSEL/32),  dim3(256),  0, stream, wp, vg, pav, nfl + 1,
                       Wo, bo, W1, b1, W2, b2, (float*)d_out);
}